// Round 2
// baseline (2097.341 us; speedup 1.0000x reference)
//
#include <hip/hip_runtime.h>
#include <math.h>

// ---------------------------------------------------------------------------
// SceneSegmenter fp32 baseline (Round 2): identical math to Round 1, but
// peak d_ws usage reduced 42 MB -> 33.55 MB (8,388,608 floats) by staging
// e0 in d_out's e-region. Defensive re-submit after two infra failures.
// Layouts: token-major activations (S, B, D) flat, row = s*8+b.
// ---------------------------------------------------------------------------

#define DEV static __device__ __forceinline__

DEV void fma4(float4& a, float s, const float4& v) {
  a.x += s * v.x; a.y += s * v.y; a.z += s * v.z; a.w += s * v.w;
}
DEV float4 zero4() { return make_float4(0.f, 0.f, 0.f, 0.f); }
DEV float4 add4(const float4& a, const float4& b) {
  return make_float4(a.x + b.x, a.y + b.y, a.z + b.z, a.w + b.w);
}
DEV float4 sub4(const float4& a, const float4& b) {
  return make_float4(a.x - b.x, a.y - b.y, a.z - b.z, a.w - b.w);
}
DEV float4 scale4(const float4& a, float s) {
  return make_float4(a.x * s, a.y * s, a.z * s, a.w * s);
}
DEV float4 relu4(const float4& a) {
  return make_float4(fmaxf(a.x, 0.f), fmaxf(a.y, 0.f), fmaxf(a.z, 0.f), fmaxf(a.w, 0.f));
}

// ---------------------------------------------------------------------------
// Generic tiled GEMM: C[M x N] = act(A[M x K](lda) @ W[N x K]^T + bias)
// BM=64, BN=128, BK=16, 256 threads, 4x8 micro-tile per thread.
// remap=1: output row r = (m & 2047)*8 + (m >> 11)   ((B,S)->(S,B) for e0)
// ---------------------------------------------------------------------------
__global__ __launch_bounds__(256) void gemm_rm(
    const float* __restrict__ A, int lda,
    const float* __restrict__ W,
    const float* __restrict__ bias,
    float* __restrict__ C,
    int M, int K, int N, int relu, int remap)
{
  __shared__ __align__(16) float As[16][68];   // [k][m]
  __shared__ __align__(16) float Bs[16][132];  // [k][n], 2-way aliasing (free)

  const int t  = threadIdx.x;
  const int m0 = blockIdx.x * 64;
  const int n0 = blockIdx.y * 128;
  const int ty = t >> 4, tx = t & 15;

  float4 acc[4][2];
#pragma unroll
  for (int i = 0; i < 4; ++i) { acc[i][0] = zero4(); acc[i][1] = zero4(); }

  const int lm = t & 63, lk = (t >> 6) << 2;   // A tile: 64 rows x 16 k
  const int bn = t & 127, bk = (t >> 7) << 3;  // B tile: 128 rows x 16 k

  for (int k0 = 0; k0 < K; k0 += 16) {
    { // load A tile
      int m = m0 + lm;
      float4 av = zero4();
      if (m < M) av = *(const float4*)(A + (size_t)m * lda + k0 + lk);
      As[lk + 0][lm] = av.x; As[lk + 1][lm] = av.y;
      As[lk + 2][lm] = av.z; As[lk + 3][lm] = av.w;
    }
    { // load B tile (N always multiple of 128 here)
      const float* wp = W + (size_t)(n0 + bn) * K + k0 + bk;
      float4 w0 = *(const float4*)(wp);
      float4 w1 = *(const float4*)(wp + 4);
      Bs[bk + 0][bn] = w0.x; Bs[bk + 1][bn] = w0.y;
      Bs[bk + 2][bn] = w0.z; Bs[bk + 3][bn] = w0.w;
      Bs[bk + 4][bn] = w1.x; Bs[bk + 5][bn] = w1.y;
      Bs[bk + 6][bn] = w1.z; Bs[bk + 7][bn] = w1.w;
    }
    __syncthreads();
#pragma unroll
    for (int k = 0; k < 16; ++k) {
      float4 a4 = *(const float4*)&As[k][4 * ty];
      float4 b0 = *(const float4*)&Bs[k][4 * tx];
      float4 b1 = *(const float4*)&Bs[k][64 + 4 * tx];
      fma4(acc[0][0], a4.x, b0); fma4(acc[0][1], a4.x, b1);
      fma4(acc[1][0], a4.y, b0); fma4(acc[1][1], a4.y, b1);
      fma4(acc[2][0], a4.z, b0); fma4(acc[2][1], a4.z, b1);
      fma4(acc[3][0], a4.w, b0); fma4(acc[3][1], a4.w, b1);
    }
    __syncthreads();
  }

  float4 bias0 = *(const float4*)(bias + n0 + 4 * tx);
  float4 bias1 = *(const float4*)(bias + n0 + 64 + 4 * tx);
#pragma unroll
  for (int i = 0; i < 4; ++i) {
    int m = m0 + 4 * ty + i;
    if (m < M) {
      float4 o0 = add4(acc[i][0], bias0);
      float4 o1 = add4(acc[i][1], bias1);
      if (relu) { o0 = relu4(o0); o1 = relu4(o1); }
      size_t r = remap ? (size_t)((m & 2047) * 8 + (m >> 11)) : (size_t)m;
      float* cp = C + r * (size_t)N + n0;
      *(float4*)(cp + 4 * tx) = o0;
      *(float4*)(cp + 64 + 4 * tx) = o1;
    }
  }
}

// ---------------------------------------------------------------------------
// Phase-1 segment GEMM: feats[16384 x 512] from x[16384 x 3584] slices.
// blockIdx.y == segment (0:place K=2048, 1:cast, 2:action, 3:audio K=512).
// ---------------------------------------------------------------------------
__global__ __launch_bounds__(256) void gemm_feats(
    const float* __restrict__ x,
    const float* __restrict__ pW, const float* __restrict__ pb,
    const float* __restrict__ cW, const float* __restrict__ cb,
    const float* __restrict__ aW, const float* __restrict__ ab,
    const float* __restrict__ uW, const float* __restrict__ ub,
    float* __restrict__ feats)
{
  __shared__ __align__(16) float As[16][68];
  __shared__ __align__(16) float Bs[16][132];

  const int seg = blockIdx.y;
  const float* W; const float* bias; int kbase, Kseg;
  if (seg == 0)      { W = pW; bias = pb; kbase = 0;    Kseg = 2048; }
  else if (seg == 1) { W = cW; bias = cb; kbase = 2048; Kseg = 512; }
  else if (seg == 2) { W = aW; bias = ab; kbase = 2560; Kseg = 512; }
  else               { W = uW; bias = ub; kbase = 3072; Kseg = 512; }

  const int t  = threadIdx.x;
  const int m0 = blockIdx.x * 64;
  const int ty = t >> 4, tx = t & 15;

  float4 acc[4][2];
#pragma unroll
  for (int i = 0; i < 4; ++i) { acc[i][0] = zero4(); acc[i][1] = zero4(); }

  const int lm = t & 63, lk = (t >> 6) << 2;
  const int bn = t & 127, bk = (t >> 7) << 3;

  for (int k0 = 0; k0 < Kseg; k0 += 16) {
    {
      int m = m0 + lm;
      float4 av = *(const float4*)(x + (size_t)m * 3584 + kbase + k0 + lk);
      As[lk + 0][lm] = av.x; As[lk + 1][lm] = av.y;
      As[lk + 2][lm] = av.z; As[lk + 3][lm] = av.w;
    }
    {
      const float* wp = W + (size_t)bn * Kseg + k0 + bk;
      float4 w0 = *(const float4*)(wp);
      float4 w1 = *(const float4*)(wp + 4);
      Bs[bk + 0][bn] = w0.x; Bs[bk + 1][bn] = w0.y;
      Bs[bk + 2][bn] = w0.z; Bs[bk + 3][bn] = w0.w;
      Bs[bk + 4][bn] = w1.x; Bs[bk + 5][bn] = w1.y;
      Bs[bk + 6][bn] = w1.z; Bs[bk + 7][bn] = w1.w;
    }
    __syncthreads();
#pragma unroll
    for (int k = 0; k < 16; ++k) {
      float4 a4 = *(const float4*)&As[k][4 * ty];
      float4 b0 = *(const float4*)&Bs[k][4 * tx];
      float4 b1 = *(const float4*)&Bs[k][64 + 4 * tx];
      fma4(acc[0][0], a4.x, b0); fma4(acc[0][1], a4.x, b1);
      fma4(acc[1][0], a4.y, b0); fma4(acc[1][1], a4.y, b1);
      fma4(acc[2][0], a4.z, b0); fma4(acc[2][1], a4.z, b1);
      fma4(acc[3][0], a4.w, b0); fma4(acc[3][1], a4.w, b1);
    }
    __syncthreads();
  }

  float4 bias0 = *(const float4*)(bias + 4 * tx);
  float4 bias1 = *(const float4*)(bias + 64 + 4 * tx);
  const int ncol = seg * 128;
#pragma unroll
  for (int i = 0; i < 4; ++i) {
    int m = m0 + 4 * ty + i;
    float4 o0 = relu4(add4(acc[i][0], bias0));
    float4 o1 = relu4(add4(acc[i][1], bias1));
    float* cp = feats + (size_t)m * 512 + ncol;
    *(float4*)(cp + 4 * tx) = o0;
    *(float4*)(cp + 64 + 4 * tx) = o1;
  }
}

// ---------------------------------------------------------------------------
// Segmentation linear: b0[16376 x 128] = relu(cat(left,right) @ beW^T + beb),
// cat rows synthesized on the fly from csum (S,B,128). K=256, N=128.
// ---------------------------------------------------------------------------
__global__ __launch_bounds__(256) void gemm_becat(
    const float* __restrict__ csum,
    const float* __restrict__ W, const float* __restrict__ bias,
    float* __restrict__ b0out)
{
  __shared__ __align__(16) float As[16][68];
  __shared__ __align__(16) float Bs[16][132];

  const int M = 16376, K = 256, N = 128;
  const int t  = threadIdx.x;
  const int m0 = blockIdx.x * 64;
  const int ty = t >> 4, tx = t & 15;

  float4 acc[4][2];
#pragma unroll
  for (int i = 0; i < 4; ++i) { acc[i][0] = zero4(); acc[i][1] = zero4(); }

  const int lm = t & 63, lk = (t >> 6) << 2;
  const int bn = t & 127, bk = (t >> 7) << 3;

  for (int k0 = 0; k0 < K; k0 += 16) {
    {
      int m = m0 + lm;
      float4 av = zero4();
      if (m < M) {
        int j = m >> 3, bb = m & 7;
        int kk = k0 + lk;
        if (kk < 128) {
          float4 v = *(const float4*)(csum + (size_t)m * 128 + kk);
          av = scale4(v, 1.f / (float)(j + 1));               // left mean
        } else {
          int d = kk - 128;
          float4 c0 = *(const float4*)(csum + (size_t)m * 128 + d);
          float4 ct = *(const float4*)(csum + (size_t)(16376 + bb) * 128 + d); // total
          av = scale4(sub4(ct, c0), 1.f / (float)(2047 - j)); // right mean
        }
      }
      As[lk + 0][lm] = av.x; As[lk + 1][lm] = av.y;
      As[lk + 2][lm] = av.z; As[lk + 3][lm] = av.w;
    }
    {
      const float* wp = W + (size_t)bn * K + k0 + bk;
      float4 w0 = *(const float4*)(wp);
      float4 w1 = *(const float4*)(wp + 4);
      Bs[bk + 0][bn] = w0.x; Bs[bk + 1][bn] = w0.y;
      Bs[bk + 2][bn] = w0.z; Bs[bk + 3][bn] = w0.w;
      Bs[bk + 4][bn] = w1.x; Bs[bk + 5][bn] = w1.y;
      Bs[bk + 6][bn] = w1.z; Bs[bk + 7][bn] = w1.w;
    }
    __syncthreads();
#pragma unroll
    for (int k = 0; k < 16; ++k) {
      float4 a4 = *(const float4*)&As[k][4 * ty];
      float4 b0 = *(const float4*)&Bs[k][4 * tx];
      float4 b1 = *(const float4*)&Bs[k][64 + 4 * tx];
      fma4(acc[0][0], a4.x, b0); fma4(acc[0][1], a4.x, b1);
      fma4(acc[1][0], a4.y, b0); fma4(acc[1][1], a4.y, b1);
      fma4(acc[2][0], a4.z, b0); fma4(acc[2][1], a4.z, b1);
      fma4(acc[3][0], a4.w, b0); fma4(acc[3][1], a4.w, b1);
    }
    __syncthreads();
  }

  float4 bias0 = *(const float4*)(bias + 4 * tx);
  float4 bias1 = *(const float4*)(bias + 64 + 4 * tx);
#pragma unroll
  for (int i = 0; i < 4; ++i) {
    int m = m0 + 4 * ty + i;
    if (m < M) {
      float4 o0 = relu4(add4(acc[i][0], bias0));
      float4 o1 = relu4(add4(acc[i][1], bias1));
      float* cp = b0out + (size_t)m * N;
      *(float4*)(cp + 4 * tx) = o0;
      *(float4*)(cp + 64 + 4 * tx) = o1;
    }
  }
}

// ---------------------------------------------------------------------------
// Flash attention (fp32, single head, D=128). proj rows = (s*8+b)*384,
// q at +0, k at +128, v at +256. out rows = (s*8+b)*128.
// TQ=TK=32, 256 threads, online softmax. LDS ~55.7 KB -> 2 blocks/CU.
// ---------------------------------------------------------------------------
__global__ __launch_bounds__(256) void attn_kernel(
    const float* __restrict__ proj, float* __restrict__ out, int Slen)
{
  __shared__ __align__(16) float Qs[32][132];
  __shared__ __align__(16) float Ks[32][132];
  __shared__ __align__(16) float Vs[32][132];
  __shared__ float Ps[32][36];
  __shared__ float mS[32], lS[32], aS[32];

  const int t  = threadIdx.x;
  const int b  = blockIdx.y;
  const int q0 = blockIdx.x * 32;
  const float scl = 0.08838834764831845f;   // 1/sqrt(128)

  { // load Q tile (pre-scaled)
    int row = t >> 3;
    int cb  = (t & 7) * 4;
    int qg  = q0 + row;
    const float* src = proj + ((size_t)qg * 8 + b) * 384;
#pragma unroll
    for (int i = 0; i < 4; ++i) {
      int c = cb + 32 * i;
      float4 v = zero4();
      if (qg < Slen) v = *(const float4*)(src + c);
      *(float4*)&Qs[row][c] = scale4(v, scl);
    }
  }
  if (t < 32) { mS[t] = -INFINITY; lS[t] = 0.f; aS[t] = 0.f; }

  float4 o[2][2];
  o[0][0] = zero4(); o[0][1] = zero4(); o[1][0] = zero4(); o[1][1] = zero4();

  const int tq = t >> 4, tx = t & 15;
  const int ntiles = (Slen + 31) >> 5;

  for (int kt = 0; kt < ntiles; ++kt) {
    __syncthreads();           // prev PV done (and Q/state init on iter 0)
    { // load K/V tiles
      int row = t >> 3;
      int cb  = (t & 7) * 4;
      int kg  = kt * 32 + row;
      const float* kp = proj + ((size_t)kg * 8 + b) * 384 + 128;
#pragma unroll
      for (int i = 0; i < 4; ++i) {
        int c = cb + 32 * i;
        float4 kv = zero4(), vv = zero4();
        if (kg < Slen) {
          kv = *(const float4*)(kp + c);
          vv = *(const float4*)(kp + 128 + c);
        }
        *(float4*)&Ks[row][c] = kv;
        *(float4*)&Vs[row][c] = vv;
      }
    }
    __syncthreads();

    // ---- scores: 2x2 per thread, rows {tq, tq+16}, cols {tx, tx+16}
    float s00 = 0.f, s01 = 0.f, s10 = 0.f, s11 = 0.f;
#pragma unroll
    for (int kk = 0; kk < 128; kk += 4) {
      float4 qa = *(const float4*)&Qs[tq][kk];
      float4 qb = *(const float4*)&Qs[tq + 16][kk];
      float4 ka = *(const float4*)&Ks[tx][kk];
      float4 kb = *(const float4*)&Ks[tx + 16][kk];
      s00 += qa.x * ka.x + qa.y * ka.y + qa.z * ka.z + qa.w * ka.w;
      s01 += qa.x * kb.x + qa.y * kb.y + qa.z * kb.z + qa.w * kb.w;
      s10 += qb.x * ka.x + qb.y * ka.y + qb.z * ka.z + qb.w * ka.w;
      s11 += qb.x * kb.x + qb.y * kb.y + qb.z * kb.z + qb.w * kb.w;
    }
    if (kt * 32 + tx >= Slen)      { s00 = -1e30f; s10 = -1e30f; }
    if (kt * 32 + tx + 16 >= Slen) { s01 = -1e30f; s11 = -1e30f; }

    // ---- online softmax per row (16-lane groups share a row)
#pragma unroll
    for (int a = 0; a < 2; ++a) {
      float x0 = a ? s10 : s00;
      float x1 = a ? s11 : s01;
      float mx = fmaxf(x0, x1);
      mx = fmaxf(mx, __shfl_xor(mx, 1));
      mx = fmaxf(mx, __shfl_xor(mx, 2));
      mx = fmaxf(mx, __shfl_xor(mx, 4));
      mx = fmaxf(mx, __shfl_xor(mx, 8));
      int qi = tq + 16 * a;
      float mOld = mS[qi];
      float mNew = fmaxf(mOld, mx);
      float p0 = __expf(x0 - mNew);
      float p1 = __expf(x1 - mNew);
      float ps = p0 + p1;
      ps += __shfl_xor(ps, 1);
      ps += __shfl_xor(ps, 2);
      ps += __shfl_xor(ps, 4);
      ps += __shfl_xor(ps, 8);
      float alpha = __expf(mOld - mNew);   // exp(-inf)=0 on first tile
      if (tx == 0) {
        mS[qi] = mNew;
        lS[qi] = lS[qi] * alpha + ps;
        aS[qi] = alpha;
      }
      Ps[qi][tx]      = p0;
      Ps[qi][tx + 16] = p1;
    }
    __syncthreads();

    // ---- PV: rows {2tq, 2tq+1}, cols f4 {tx, tx+16}
    {
      float al0 = aS[2 * tq + 0];
      float al1 = aS[2 * tq + 1];
      o[0][0] = scale4(o[0][0], al0); o[0][1] = scale4(o[0][1], al0);
      o[1][0] = scale4(o[1][0], al1); o[1][1] = scale4(o[1][1], al1);
#pragma unroll
      for (int kj = 0; kj < 32; ++kj) {
        float p0 = Ps[2 * tq + 0][kj];
        float p1 = Ps[2 * tq + 1][kj];
        float4 v0 = *(const float4*)&Vs[kj][4 * tx];
        float4 v1 = *(const float4*)&Vs[kj][64 + 4 * tx];
        fma4(o[0][0], p0, v0); fma4(o[0][1], p0, v1);
        fma4(o[1][0], p1, v0); fma4(o[1][1], p1, v1);
      }
    }
  }
  __syncthreads();

#pragma unroll
  for (int a = 0; a < 2; ++a) {
    int qi = 2 * tq + a;
    int qg = q0 + qi;
    if (qg < Slen) {
      float inv = 1.f / lS[qi];
      float* dst = out + ((size_t)qg * 8 + b) * 128;
      *(float4*)(dst + 4 * tx)      = scale4(o[a][0], inv);
      *(float4*)(dst + 64 + 4 * tx) = scale4(o[a][1], inv);
    }
  }
}

// ---------------------------------------------------------------------------
// 3-phase cumsum over s of e (S,B,128) -> csum, chunked 16 x 128.
// ---------------------------------------------------------------------------
__global__ void cumsum_p1(const float* __restrict__ e, float* __restrict__ csum,
                          float* __restrict__ part)
{
  int chunk = blockIdx.x, b = blockIdx.y, d = threadIdx.x;
  float run = 0.f;
  int s0 = chunk * 128;
  for (int s = 0; s < 128; ++s) {
    size_t idx = ((size_t)(s0 + s) * 8 + b) * 128 + d;
    run += e[idx];
    csum[idx] = run;
  }
  part[(b * 16 + chunk) * 128 + d] = run;
}

__global__ void cumsum_p2(float* __restrict__ part)
{
  int b = blockIdx.x, d = threadIdx.x;
  float run = 0.f;
  for (int c = 0; c < 16; ++c) {
    float v = part[(b * 16 + c) * 128 + d];
    part[(b * 16 + c) * 128 + d] = run;   // exclusive offsets
    run += v;
  }
}

__global__ void cumsum_p3(float* __restrict__ csum, const float* __restrict__ part)
{
  int chunk = blockIdx.x, b = blockIdx.y, d = threadIdx.x;
  float off = part[(b * 16 + chunk) * 128 + d];
  int s0 = chunk * 128;
  for (int s = 0; s < 128; ++s)
    csum[((size_t)(s0 + s) * 8 + b) * 128 + d] += off;
}

// ---------------------------------------------------------------------------
// Final head: out[j*8+b] = sigmoid(dot(bout_row, bpW) + bpb). One wave/row.
// ---------------------------------------------------------------------------
__global__ __launch_bounds__(256) void final_bp(
    const float* __restrict__ bout, const float* __restrict__ bpW,
    const float* __restrict__ bpb, float* __restrict__ out, int M)
{
  int row  = blockIdx.x * 4 + (threadIdx.x >> 6);
  int lane = threadIdx.x & 63;
  if (row >= M) return;
  const float* src = bout + (size_t)row * 128;
  float2 v = *(const float2*)(src + lane * 2);
  float2 w = *(const float2*)(bpW + lane * 2);
  float p = v.x * w.x + v.y * w.y;
  p += __shfl_xor(p, 1);  p += __shfl_xor(p, 2);  p += __shfl_xor(p, 4);
  p += __shfl_xor(p, 8);  p += __shfl_xor(p, 16); p += __shfl_xor(p, 32);
  if (lane == 0) out[row] = 1.f / (1.f + __expf(-(p + bpb[0])));
}

// ---------------------------------------------------------------------------
extern "C" void kernel_launch(void* const* d_in, const int* in_sizes, int n_in,
                              void* d_out, int out_size, void* d_ws, size_t ws_size,
                              hipStream_t stream)
{
  const float* x       = (const float*)d_in[0];
  const float* pW      = (const float*)d_in[1];
  const float* pb      = (const float*)d_in[2];
  const float* cW      = (const float*)d_in[3];
  const float* cb      = (const float*)d_in[4];
  const float* aW      = (const float*)d_in[5];
  const float* ab      = (const float*)d_in[6];
  const float* uW      = (const float*)d_in[7];
  const float* ub      = (const float*)d_in[8];
  const float* eW      = (const float*)d_in[9];
  const float* eb      = (const float*)d_in[10];
  const float* la_win  = (const float*)d_in[11];
  const float* la_bin  = (const float*)d_in[12];
  const float* la_wout = (const float*)d_in[13];
  const float* la_bout = (const float*)d_in[14];
  const float* beW     = (const float*)d_in[15];
  const float* beb     = (const float*)d_in[16];
  const float* ba_win  = (const float*)d_in[17];
  const float* ba_bin  = (const float*)d_in[18];
  const float* ba_wout = (const float*)d_in[19];
  const float* ba_bout = (const float*)d_in[20];
  const float* bpW     = (const float*)d_in[21];
  const float* bpb     = (const float*)d_in[22];

  float* ws   = (float*)d_ws;
  float* outF = (float*)d_out;

  // Workspace plan (peak 8,388,608 floats = 33.55 MB), all aliases serial:
  // Phase A: feats ws[0,8.39M) ; e0 -> outF ; proj1 ws[0,6.29M) ;
  //          att1 ws[6.29M,8.39M) ; e -> outF.
  // Phase B: csum ws[0,2.10M) + part ; b0 ws[6.29M,8.39M) ;
  //          proj2 ws[0,6.29M) ; att2 ws[6.29M,8.39M) ;
  //          bout ws[0,2.10M) ; b -> outF tail.
  float* featsB = ws;                 // 16384*512
  float* e0B    = outF;               // 16384*128 (scratch until step 5)
  float* proj1B = ws;                 // 16384*384
  float* att1B  = ws + 6291456;       // 16384*128
  float* csumB  = ws;                 // 16384*128
  float* partB  = ws + 2097152;       // 8*16*128
  float* b0B    = ws + 6291456;       // 16376*128
  float* proj2B = ws;                 // 16376*384
  float* att2B  = ws + 6291456;       // 16376*128
  float* boutB  = ws;                 // 16376*128

  // 1. feats = relu(segment linears)              (B,S) rows, 16384 x 512
  gemm_feats<<<dim3(256, 4), 256, 0, stream>>>(x, pW, pb, cW, cb, aW, ab, uW, ub, featsB);
  // 2. e0 = relu(feats @ eW^T + eb), remapped to (S,B) rows -> outF
  gemm_rm<<<dim3(256, 1), 256, 0, stream>>>(featsB, 512, eW, eb, e0B,
                                            16384, 512, 128, 1, 1);
  // 3. proj1 = e0 @ la_win^T + la_bin   (16384 x 384)
  gemm_rm<<<dim3(256, 3), 256, 0, stream>>>(e0B, 128, la_win, la_bin, proj1B,
                                            16384, 128, 384, 0, 0);
  // 4. att1 = softmax(QK^T/sqrt(128)) V
  attn_kernel<<<dim3(64, 8), 256, 0, stream>>>(proj1B, att1B, 2048);
  // 5. e = att1 @ la_wout^T + la_bout  -> d_out (S,B,128)
  gemm_rm<<<dim3(256, 1), 256, 0, stream>>>(att1B, 128, la_wout, la_bout, outF,
                                            16384, 128, 128, 0, 0);
  // 6-8. csum = cumsum_s(e)
  cumsum_p1<<<dim3(16, 8), 128, 0, stream>>>(outF, csumB, partB);
  cumsum_p2<<<dim3(8), 128, 0, stream>>>(partB);
  cumsum_p3<<<dim3(16, 8), 128, 0, stream>>>(csumB, partB);
  // 9. b0 = relu(cat(left,right) @ beW^T + beb)   (16376 x 128)
  gemm_becat<<<dim3(256, 1), 256, 0, stream>>>(csumB, beW, beb, b0B);
  // 10. proj2 = b0 @ ba_win^T + ba_bin
  gemm_rm<<<dim3(256, 3), 256, 0, stream>>>(b0B, 128, ba_win, ba_bin, proj2B,
                                            16376, 128, 384, 0, 0);
  // 11. att2 (Slen = 2047)
  attn_kernel<<<dim3(64, 8), 256, 0, stream>>>(proj2B, att2B, 2047);
  // 12. bout = att2 @ ba_wout^T + ba_bout
  gemm_rm<<<dim3(256, 1), 256, 0, stream>>>(att2B, 128, ba_wout, ba_bout, boutB,
                                            16376, 128, 128, 0, 0);
  // 13. b = sigmoid(bout @ bpW^T + bpb)  -> d_out tail (S-1,B)
  final_bp<<<dim3(4094), 256, 0, stream>>>(boutB, bpW, bpb, outF + 2097152, 16376);
}

// Round 3
// 1056.378 us; speedup vs baseline: 1.9854x; 1.9854x over previous
//
#include <hip/hip_runtime.h>
#include <math.h>
#include <stdint.h>

// ---------------------------------------------------------------------------
// SceneSegmenter Round 3: attention moved to bf16 MFMA (16x16x32), all other
// kernels identical to the passing Round-2 fp32 versions.
// Layouts: token-major activations (S, B, D) flat, row = s*8+b.
// ---------------------------------------------------------------------------

#define DEV static __device__ __forceinline__

typedef __attribute__((ext_vector_type(8))) short bf16x8;   // 8 bf16 (4 VGPRs)
typedef __attribute__((ext_vector_type(4))) float f32x4;    // MFMA C/D

DEV void fma4(float4& a, float s, const float4& v) {
  a.x += s * v.x; a.y += s * v.y; a.z += s * v.z; a.w += s * v.w;
}
DEV float4 zero4() { return make_float4(0.f, 0.f, 0.f, 0.f); }
DEV float4 add4(const float4& a, const float4& b) {
  return make_float4(a.x + b.x, a.y + b.y, a.z + b.z, a.w + b.w);
}
DEV float4 sub4(const float4& a, const float4& b) {
  return make_float4(a.x - b.x, a.y - b.y, a.z - b.z, a.w - b.w);
}
DEV float4 scale4(const float4& a, float s) {
  return make_float4(a.x * s, a.y * s, a.z * s, a.w * s);
}
DEV float4 relu4(const float4& a) {
  return make_float4(fmaxf(a.x, 0.f), fmaxf(a.y, 0.f), fmaxf(a.z, 0.f), fmaxf(a.w, 0.f));
}
DEV uint16_t f2bf(float f) {          // fp32 -> bf16, round-to-nearest-even
  union { float f; uint32_t u; } v; v.f = f;
  uint32_t u = v.u;
  return (uint16_t)((u + 0x7FFFu + ((u >> 16) & 1u)) >> 16);
}

// ---------------------------------------------------------------------------
// Generic tiled fp32 GEMM (unchanged from Round 2, verified passing).
// ---------------------------------------------------------------------------
__global__ __launch_bounds__(256) void gemm_rm(
    const float* __restrict__ A, int lda,
    const float* __restrict__ W,
    const float* __restrict__ bias,
    float* __restrict__ C,
    int M, int K, int N, int relu, int remap)
{
  __shared__ __align__(16) float As[16][68];
  __shared__ __align__(16) float Bs[16][132];

  const int t  = threadIdx.x;
  const int m0 = blockIdx.x * 64;
  const int n0 = blockIdx.y * 128;
  const int ty = t >> 4, tx = t & 15;

  float4 acc[4][2];
#pragma unroll
  for (int i = 0; i < 4; ++i) { acc[i][0] = zero4(); acc[i][1] = zero4(); }

  const int lm = t & 63, lk = (t >> 6) << 2;
  const int bn = t & 127, bk = (t >> 7) << 3;

  for (int k0 = 0; k0 < K; k0 += 16) {
    {
      int m = m0 + lm;
      float4 av = zero4();
      if (m < M) av = *(const float4*)(A + (size_t)m * lda + k0 + lk);
      As[lk + 0][lm] = av.x; As[lk + 1][lm] = av.y;
      As[lk + 2][lm] = av.z; As[lk + 3][lm] = av.w;
    }
    {
      const float* wp = W + (size_t)(n0 + bn) * K + k0 + bk;
      float4 w0 = *(const float4*)(wp);
      float4 w1 = *(const float4*)(wp + 4);
      Bs[bk + 0][bn] = w0.x; Bs[bk + 1][bn] = w0.y;
      Bs[bk + 2][bn] = w0.z; Bs[bk + 3][bn] = w0.w;
      Bs[bk + 4][bn] = w1.x; Bs[bk + 5][bn] = w1.y;
      Bs[bk + 6][bn] = w1.z; Bs[bk + 7][bn] = w1.w;
    }
    __syncthreads();
#pragma unroll
    for (int k = 0; k < 16; ++k) {
      float4 a4 = *(const float4*)&As[k][4 * ty];
      float4 b0 = *(const float4*)&Bs[k][4 * tx];
      float4 b1 = *(const float4*)&Bs[k][64 + 4 * tx];
      fma4(acc[0][0], a4.x, b0); fma4(acc[0][1], a4.x, b1);
      fma4(acc[1][0], a4.y, b0); fma4(acc[1][1], a4.y, b1);
      fma4(acc[2][0], a4.z, b0); fma4(acc[2][1], a4.z, b1);
      fma4(acc[3][0], a4.w, b0); fma4(acc[3][1], a4.w, b1);
    }
    __syncthreads();
  }

  float4 bias0 = *(const float4*)(bias + n0 + 4 * tx);
  float4 bias1 = *(const float4*)(bias + n0 + 64 + 4 * tx);
#pragma unroll
  for (int i = 0; i < 4; ++i) {
    int m = m0 + 4 * ty + i;
    if (m < M) {
      float4 o0 = add4(acc[i][0], bias0);
      float4 o1 = add4(acc[i][1], bias1);
      if (relu) { o0 = relu4(o0); o1 = relu4(o1); }
      size_t r = remap ? (size_t)((m & 2047) * 8 + (m >> 11)) : (size_t)m;
      float* cp = C + r * (size_t)N + n0;
      *(float4*)(cp + 4 * tx) = o0;
      *(float4*)(cp + 64 + 4 * tx) = o1;
    }
  }
}

// ---------------------------------------------------------------------------
// Phase-1 segment GEMM (unchanged).
// ---------------------------------------------------------------------------
__global__ __launch_bounds__(256) void gemm_feats(
    const float* __restrict__ x,
    const float* __restrict__ pW, const float* __restrict__ pb,
    const float* __restrict__ cW, const float* __restrict__ cb,
    const float* __restrict__ aW, const float* __restrict__ ab,
    const float* __restrict__ uW, const float* __restrict__ ub,
    float* __restrict__ feats)
{
  __shared__ __align__(16) float As[16][68];
  __shared__ __align__(16) float Bs[16][132];

  const int seg = blockIdx.y;
  const float* W; const float* bias; int kbase, Kseg;
  if (seg == 0)      { W = pW; bias = pb; kbase = 0;    Kseg = 2048; }
  else if (seg == 1) { W = cW; bias = cb; kbase = 2048; Kseg = 512; }
  else if (seg == 2) { W = aW; bias = ab; kbase = 2560; Kseg = 512; }
  else               { W = uW; bias = ub; kbase = 3072; Kseg = 512; }

  const int t  = threadIdx.x;
  const int m0 = blockIdx.x * 64;
  const int ty = t >> 4, tx = t & 15;

  float4 acc[4][2];
#pragma unroll
  for (int i = 0; i < 4; ++i) { acc[i][0] = zero4(); acc[i][1] = zero4(); }

  const int lm = t & 63, lk = (t >> 6) << 2;
  const int bn = t & 127, bk = (t >> 7) << 3;

  for (int k0 = 0; k0 < Kseg; k0 += 16) {
    {
      int m = m0 + lm;
      float4 av = *(const float4*)(x + (size_t)m * 3584 + kbase + k0 + lk);
      As[lk + 0][lm] = av.x; As[lk + 1][lm] = av.y;
      As[lk + 2][lm] = av.z; As[lk + 3][lm] = av.w;
    }
    {
      const float* wp = W + (size_t)bn * Kseg + k0 + bk;
      float4 w0 = *(const float4*)(wp);
      float4 w1 = *(const float4*)(wp + 4);
      Bs[bk + 0][bn] = w0.x; Bs[bk + 1][bn] = w0.y;
      Bs[bk + 2][bn] = w0.z; Bs[bk + 3][bn] = w0.w;
      Bs[bk + 4][bn] = w1.x; Bs[bk + 5][bn] = w1.y;
      Bs[bk + 6][bn] = w1.z; Bs[bk + 7][bn] = w1.w;
    }
    __syncthreads();
#pragma unroll
    for (int k = 0; k < 16; ++k) {
      float4 a4 = *(const float4*)&As[k][4 * ty];
      float4 b0 = *(const float4*)&Bs[k][4 * tx];
      float4 b1 = *(const float4*)&Bs[k][64 + 4 * tx];
      fma4(acc[0][0], a4.x, b0); fma4(acc[0][1], a4.x, b1);
      fma4(acc[1][0], a4.y, b0); fma4(acc[1][1], a4.y, b1);
      fma4(acc[2][0], a4.z, b0); fma4(acc[2][1], a4.z, b1);
      fma4(acc[3][0], a4.w, b0); fma4(acc[3][1], a4.w, b1);
    }
    __syncthreads();
  }

  float4 bias0 = *(const float4*)(bias + 4 * tx);
  float4 bias1 = *(const float4*)(bias + 64 + 4 * tx);
  const int ncol = seg * 128;
#pragma unroll
  for (int i = 0; i < 4; ++i) {
    int m = m0 + 4 * ty + i;
    float4 o0 = relu4(add4(acc[i][0], bias0));
    float4 o1 = relu4(add4(acc[i][1], bias1));
    float* cp = feats + (size_t)m * 512 + ncol;
    *(float4*)(cp + 4 * tx) = o0;
    *(float4*)(cp + 64 + 4 * tx) = o1;
  }
}

// ---------------------------------------------------------------------------
// Segmentation linear (unchanged).
// ---------------------------------------------------------------------------
__global__ __launch_bounds__(256) void gemm_becat(
    const float* __restrict__ csum,
    const float* __restrict__ W, const float* __restrict__ bias,
    float* __restrict__ b0out)
{
  __shared__ __align__(16) float As[16][68];
  __shared__ __align__(16) float Bs[16][132];

  const int M = 16376, K = 256, N = 128;
  const int t  = threadIdx.x;
  const int m0 = blockIdx.x * 64;
  const int ty = t >> 4, tx = t & 15;

  float4 acc[4][2];
#pragma unroll
  for (int i = 0; i < 4; ++i) { acc[i][0] = zero4(); acc[i][1] = zero4(); }

  const int lm = t & 63, lk = (t >> 6) << 2;
  const int bn = t & 127, bk = (t >> 7) << 3;

  for (int k0 = 0; k0 < K; k0 += 16) {
    {
      int m = m0 + lm;
      float4 av = zero4();
      if (m < M) {
        int j = m >> 3, bb = m & 7;
        int kk = k0 + lk;
        if (kk < 128) {
          float4 v = *(const float4*)(csum + (size_t)m * 128 + kk);
          av = scale4(v, 1.f / (float)(j + 1));
        } else {
          int d = kk - 128;
          float4 c0 = *(const float4*)(csum + (size_t)m * 128 + d);
          float4 ct = *(const float4*)(csum + (size_t)(16376 + bb) * 128 + d);
          av = scale4(sub4(ct, c0), 1.f / (float)(2047 - j));
        }
      }
      As[lk + 0][lm] = av.x; As[lk + 1][lm] = av.y;
      As[lk + 2][lm] = av.z; As[lk + 3][lm] = av.w;
    }
    {
      const float* wp = W + (size_t)bn * K + k0 + bk;
      float4 w0 = *(const float4*)(wp);
      float4 w1 = *(const float4*)(wp + 4);
      Bs[bk + 0][bn] = w0.x; Bs[bk + 1][bn] = w0.y;
      Bs[bk + 2][bn] = w0.z; Bs[bk + 3][bn] = w0.w;
      Bs[bk + 4][bn] = w1.x; Bs[bk + 5][bn] = w1.y;
      Bs[bk + 6][bn] = w1.z; Bs[bk + 7][bn] = w1.w;
    }
    __syncthreads();
#pragma unroll
    for (int k = 0; k < 16; ++k) {
      float4 a4 = *(const float4*)&As[k][4 * ty];
      float4 b0 = *(const float4*)&Bs[k][4 * tx];
      float4 b1 = *(const float4*)&Bs[k][64 + 4 * tx];
      fma4(acc[0][0], a4.x, b0); fma4(acc[0][1], a4.x, b1);
      fma4(acc[1][0], a4.y, b0); fma4(acc[1][1], a4.y, b1);
      fma4(acc[2][0], a4.z, b0); fma4(acc[2][1], a4.z, b1);
      fma4(acc[3][0], a4.w, b0); fma4(acc[3][1], a4.w, b1);
    }
    __syncthreads();
  }

  float4 bias0 = *(const float4*)(bias + 4 * tx);
  float4 bias1 = *(const float4*)(bias + 64 + 4 * tx);
#pragma unroll
  for (int i = 0; i < 4; ++i) {
    int m = m0 + 4 * ty + i;
    if (m < M) {
      float4 o0 = relu4(add4(acc[i][0], bias0));
      float4 o1 = relu4(add4(acc[i][1], bias1));
      float* cp = b0out + (size_t)m * N;
      *(float4*)(cp + 4 * tx) = o0;
      *(float4*)(cp + 64 + 4 * tx) = o1;
    }
  }
}

// ---------------------------------------------------------------------------
// Flash attention, bf16 MFMA (16x16x32). 256 threads = 4 waves.
// Q-tile 64 (16 rows/wave, frags in regs), K-tile 64/iter.
// Fragment layouts (verified m89/m91/m120):
//   A[m][k]: m = lane&15, k = (lane>>4)*8 + j      (8 contiguous bf16 -> b128)
//   B[k][n]: n = lane&15, k = (lane>>4)*8 + j
//   C/D    : col = lane&15, row = (lane>>4)*4 + reg
// V staged transposed with permuted key order k' = (k&15)*4 + (k>>4); P uses
// the same permutation, so the PV key-sum is order-invariant and both P-writes
// (ds_write_b64) and A/B reads (ds_read_b128) are contiguous.
// Softmax state (m,l) in registers, replicated per 16-lane quad.
// LDS: K 17.4 KB + Vt 18.4 KB + P 9.2 KB = 44 KB.
// ---------------------------------------------------------------------------
__global__ __launch_bounds__(256) void attn_mfma(
    const float* __restrict__ proj, float* __restrict__ out, int Slen)
{
  __shared__ __align__(16) uint16_t KsL[64 * 136];     // [key][k], pitch 136
  __shared__ __align__(16) uint16_t VtL[128 * 72];     // [d][k'],  pitch 72
  __shared__ __align__(16) uint16_t PbL[4][16 * 72];   // per-wave [q][k']

  const int t  = threadIdx.x;
  const int b  = blockIdx.y;
  const int q0 = blockIdx.x * 64;
  const int w  = t >> 6;           // wave id 0..3
  const int l  = t & 63;
  const int ln = l & 15;
  const int qd = l >> 4;           // quad 0..3
  const float scl = 0.08838834764831845f;   // 1/sqrt(128)

  // ---- Q fragments: rows q0 + w*16 + ln, 4 k-steps, pre-scaled, in regs
  bf16x8 qf[4];
  {
    int qrow = q0 + w * 16 + ln;
    int qc = qrow < Slen ? qrow : Slen - 1;
    const float* qp = proj + ((size_t)qc * 8 + b) * 384 + qd * 8;
#pragma unroll
    for (int ks = 0; ks < 4; ++ks) {
      float4 f0 = *(const float4*)(qp + ks * 32);
      float4 f1 = *(const float4*)(qp + ks * 32 + 4);
      union { bf16x8 v; uint16_t u[8]; } pk;
      pk.u[0] = f2bf(f0.x * scl); pk.u[1] = f2bf(f0.y * scl);
      pk.u[2] = f2bf(f0.z * scl); pk.u[3] = f2bf(f0.w * scl);
      pk.u[4] = f2bf(f1.x * scl); pk.u[5] = f2bf(f1.y * scl);
      pk.u[6] = f2bf(f1.z * scl); pk.u[7] = f2bf(f1.w * scl);
      qf[ks] = pk.v;
    }
  }

  f32x4 oacc[8];
#pragma unroll
  for (int i = 0; i < 8; ++i) oacc[i] = (f32x4){0.f, 0.f, 0.f, 0.f};
  float mrow[4] = {-INFINITY, -INFINITY, -INFINITY, -INFINITY};
  float lrow[4] = {0.f, 0.f, 0.f, 0.f};

  const int ntiles = (Slen + 63) >> 6;
  for (int kt = 0; kt < ntiles; ++kt) {
    __syncthreads();   // all waves done reading previous K/V
    { // ---- stage K tile: Ks[key][0..128), bf16
      int key = t >> 2;
      int kb  = (t & 3) * 32;
      int kg  = kt * 64 + key;
      int kc  = kg < Slen ? kg : Slen - 1;
      const float* kp = proj + ((size_t)kc * 8 + b) * 384 + 128 + kb;
      uint16_t* dst = KsL + key * 136 + kb;
#pragma unroll
      for (int i = 0; i < 4; ++i) {
        float4 f0 = *(const float4*)(kp + i * 8);
        float4 f1 = *(const float4*)(kp + i * 8 + 4);
        union { bf16x8 v; uint16_t u[8]; } pk;
        pk.u[0] = f2bf(f0.x); pk.u[1] = f2bf(f0.y);
        pk.u[2] = f2bf(f0.z); pk.u[3] = f2bf(f0.w);
        pk.u[4] = f2bf(f1.x); pk.u[5] = f2bf(f1.y);
        pk.u[6] = f2bf(f1.z); pk.u[7] = f2bf(f1.w);
        *(bf16x8*)(dst + i * 8) = pk.v;
      }
    }
    { // ---- stage V transposed+permuted: Vt[d][k'], keys (k, k+16) pack b32
      int pi  = t & 31;
      int k0o = (pi & 15) + ((pi >> 4) << 5);       // 0..15, 32..47
      int d0  = (t >> 5) * 16;
      int kg0 = kt * 64 + k0o, kg1 = kg0 + 16;
      int kc0 = kg0 < Slen ? kg0 : Slen - 1;
      int kc1 = kg1 < Slen ? kg1 : Slen - 1;
      const float* v0p = proj + ((size_t)kc0 * 8 + b) * 384 + 256 + d0;
      const float* v1p = proj + ((size_t)kc1 * 8 + b) * 384 + 256 + d0;
      int kpos = (k0o & 15) * 4 + (k0o >> 4);       // even; partner at +1
#pragma unroll
      for (int i = 0; i < 4; ++i) {
        float4 a = *(const float4*)(v0p + i * 4);
        float4 c = *(const float4*)(v1p + i * 4);
        float av[4] = {a.x, a.y, a.z, a.w};
        float cv[4] = {c.x, c.y, c.z, c.w};
#pragma unroll
        for (int j = 0; j < 4; ++j) {
          uint32_t pk = (uint32_t)f2bf(av[j]) | ((uint32_t)f2bf(cv[j]) << 16);
          *(uint32_t*)(VtL + (size_t)(d0 + i * 4 + j) * 72 + kpos) = pk;
        }
      }
    }
    __syncthreads();   // staging visible

    // ---- scores: S(16x64) per wave = 4 n-frags x 4 k-steps MFMA
    f32x4 sc[4];
#pragma unroll
    for (int nf = 0; nf < 4; ++nf) {
      f32x4 acc = (f32x4){0.f, 0.f, 0.f, 0.f};
#pragma unroll
      for (int ks = 0; ks < 4; ++ks) {
        bf16x8 kf = *(const bf16x8*)(KsL + (size_t)(nf * 16 + ln) * 136 + ks * 32 + qd * 8);
        acc = __builtin_amdgcn_mfma_f32_16x16x32_bf16(qf[ks], kf, acc, 0, 0, 0);
      }
      int key = kt * 64 + nf * 16 + ln;
      if (key >= Slen) { acc[0] = -1e30f; acc[1] = -1e30f; acc[2] = -1e30f; acc[3] = -1e30f; }
      sc[nf] = acc;
    }

    // ---- online softmax (row = qd*4+r, cols across 16 lanes x 4 nf)
    float alphaR[4];
#pragma unroll
    for (int r = 0; r < 4; ++r) {
      float mx = fmaxf(fmaxf(sc[0][r], sc[1][r]), fmaxf(sc[2][r], sc[3][r]));
      mx = fmaxf(mx, __shfl_xor(mx, 1));
      mx = fmaxf(mx, __shfl_xor(mx, 2));
      mx = fmaxf(mx, __shfl_xor(mx, 4));
      mx = fmaxf(mx, __shfl_xor(mx, 8));
      float mNew = fmaxf(mrow[r], mx);
      float p0 = __expf(sc[0][r] - mNew);
      float p1 = __expf(sc[1][r] - mNew);
      float p2 = __expf(sc[2][r] - mNew);
      float p3 = __expf(sc[3][r] - mNew);
      float ps = p0 + p1 + p2 + p3;
      ps += __shfl_xor(ps, 1);
      ps += __shfl_xor(ps, 2);
      ps += __shfl_xor(ps, 4);
      ps += __shfl_xor(ps, 8);
      float alpha = __expf(mrow[r] - mNew);
      mrow[r] = mNew;
      lrow[r] = lrow[r] * alpha + ps;
      alphaR[r] = alpha;
      // P write, permuted cols: lane's 4 nf-values contiguous at k' = ln*4+nf
      uint2 pk;
      pk.x = (uint32_t)f2bf(p0) | ((uint32_t)f2bf(p1) << 16);
      pk.y = (uint32_t)f2bf(p2) | ((uint32_t)f2bf(p3) << 16);
      *(uint2*)(PbL[w] + (size_t)(qd * 4 + r) * 72 + ln * 4) = pk;
    }
#pragma unroll
    for (int no = 0; no < 8; ++no) {
#pragma unroll
      for (int r = 0; r < 4; ++r) oacc[no][r] *= alphaR[r];
    }
    // drain P writes (cross-lane within wave through LDS; no barrier needed)
    __asm__ volatile("s_waitcnt lgkmcnt(0)" ::: "memory");

    // ---- PV: O(16x128) += P(16x64) @ V(64x128), permuted k-order
#pragma unroll
    for (int ks2 = 0; ks2 < 2; ++ks2) {
      bf16x8 af = *(const bf16x8*)(PbL[w] + (size_t)ln * 72 + ks2 * 32 + qd * 8);
#pragma unroll
      for (int no = 0; no < 8; ++no) {
        bf16x8 vf = *(const bf16x8*)(VtL + (size_t)(no * 16 + ln) * 72 + ks2 * 32 + qd * 8);
        oacc[no] = __builtin_amdgcn_mfma_f32_16x16x32_bf16(af, vf, oacc[no], 0, 0, 0);
      }
    }
  }

  // ---- epilogue: normalize and store (C-layout: row = qd*4+r, col = no*16+ln)
#pragma unroll
  for (int r = 0; r < 4; ++r) {
    int qg = q0 + w * 16 + qd * 4 + r;
    if (qg < Slen) {
      float inv = 1.f / lrow[r];
      float* dst = out + ((size_t)qg * 8 + b) * 128 + ln;
#pragma unroll
      for (int no = 0; no < 8; ++no) dst[no * 16] = oacc[no][r] * inv;
    }
  }
}

// ---------------------------------------------------------------------------
// Cumsum + final head (unchanged).
// ---------------------------------------------------------------------------
__global__ void cumsum_p1(const float* __restrict__ e, float* __restrict__ csum,
                          float* __restrict__ part)
{
  int chunk = blockIdx.x, b = blockIdx.y, d = threadIdx.x;
  float run = 0.f;
  int s0 = chunk * 128;
  for (int s = 0; s < 128; ++s) {
    size_t idx = ((size_t)(s0 + s) * 8 + b) * 128 + d;
    run += e[idx];
    csum[idx] = run;
  }
  part[(b * 16 + chunk) * 128 + d] = run;
}

__global__ void cumsum_p2(float* __restrict__ part)
{
  int b = blockIdx.x, d = threadIdx.x;
  float run = 0.f;
  for (int c = 0; c < 16; ++c) {
    float v = part[(b * 16 + c) * 128 + d];
    part[(b * 16 + c) * 128 + d] = run;
    run += v;
  }
}

__global__ void cumsum_p3(float* __restrict__ csum, const float* __restrict__ part)
{
  int chunk = blockIdx.x, b = blockIdx.y, d = threadIdx.x;
  float off = part[(b * 16 + chunk) * 128 + d];
  int s0 = chunk * 128;
  for (int s = 0; s < 128; ++s)
    csum[((size_t)(s0 + s) * 8 + b) * 128 + d] += off;
}

__global__ __launch_bounds__(256) void final_bp(
    const float* __restrict__ bout, const float* __restrict__ bpW,
    const float* __restrict__ bpb, float* __restrict__ out, int M)
{
  int row  = blockIdx.x * 4 + (threadIdx.x >> 6);
  int lane = threadIdx.x & 63;
  if (row >= M) return;
  const float* src = bout + (size_t)row * 128;
  float2 v = *(const float2*)(src + lane * 2);
  float2 w = *(const float2*)(bpW + lane * 2);
  float p = v.x * w.x + v.y * w.y;
  p += __shfl_xor(p, 1);  p += __shfl_xor(p, 2);  p += __shfl_xor(p, 4);
  p += __shfl_xor(p, 8);  p += __shfl_xor(p, 16); p += __shfl_xor(p, 32);
  if (lane == 0) out[row] = 1.f / (1.f + __expf(-(p + bpb[0])));
}

// ---------------------------------------------------------------------------
extern "C" void kernel_launch(void* const* d_in, const int* in_sizes, int n_in,
                              void* d_out, int out_size, void* d_ws, size_t ws_size,
                              hipStream_t stream)
{
  const float* x       = (const float*)d_in[0];
  const float* pW      = (const float*)d_in[1];
  const float* pb      = (const float*)d_in[2];
  const float* cW      = (const float*)d_in[3];
  const float* cb      = (const float*)d_in[4];
  const float* aW      = (const float*)d_in[5];
  const float* ab      = (const float*)d_in[6];
  const float* uW      = (const float*)d_in[7];
  const float* ub      = (const float*)d_in[8];
  const float* eW      = (const float*)d_in[9];
  const float* eb      = (const float*)d_in[10];
  const float* la_win  = (const float*)d_in[11];
  const float* la_bin  = (const float*)d_in[12];
  const float* la_wout = (const float*)d_in[13];
  const float* la_bout = (const float*)d_in[14];
  const float* beW     = (const float*)d_in[15];
  const float* beb     = (const float*)d_in[16];
  const float* ba_win  = (const float*)d_in[17];
  const float* ba_bin  = (const float*)d_in[18];
  const float* ba_wout = (const float*)d_in[19];
  const float* ba_bout = (const float*)d_in[20];
  const float* bpW     = (const float*)d_in[21];
  const float* bpb     = (const float*)d_in[22];

  float* ws   = (float*)d_ws;
  float* outF = (float*)d_out;

  float* featsB = ws;                 // 16384*512
  float* e0B    = outF;               // 16384*128 (scratch until step 5)
  float* proj1B = ws;                 // 16384*384
  float* att1B  = ws + 6291456;       // 16384*128
  float* csumB  = ws;                 // 16384*128
  float* partB  = ws + 2097152;       // 8*16*128
  float* b0B    = ws + 6291456;       // 16376*128
  float* proj2B = ws;                 // 16376*384
  float* att2B  = ws + 6291456;       // 16376*128
  float* boutB  = ws;                 // 16376*128

  gemm_feats<<<dim3(256, 4), 256, 0, stream>>>(x, pW, pb, cW, cb, aW, ab, uW, ub, featsB);
  gemm_rm<<<dim3(256, 1), 256, 0, stream>>>(featsB, 512, eW, eb, e0B,
                                            16384, 512, 128, 1, 1);
  gemm_rm<<<dim3(256, 3), 256, 0, stream>>>(e0B, 128, la_win, la_bin, proj1B,
                                            16384, 128, 384, 0, 0);
  attn_mfma<<<dim3(32, 8), 256, 0, stream>>>(proj1B, att1B, 2048);
  gemm_rm<<<dim3(256, 1), 256, 0, stream>>>(att1B, 128, la_wout, la_bout, outF,
                                            16384, 128, 128, 0, 0);
  cumsum_p1<<<dim3(16, 8), 128, 0, stream>>>(outF, csumB, partB);
  cumsum_p2<<<dim3(8), 128, 0, stream>>>(partB);
  cumsum_p3<<<dim3(16, 8), 128, 0, stream>>>(csumB, partB);
  gemm_becat<<<dim3(256, 1), 256, 0, stream>>>(csumB, beW, beb, b0B);
  gemm_rm<<<dim3(256, 3), 256, 0, stream>>>(b0B, 128, ba_win, ba_bin, proj2B,
                                            16376, 128, 384, 0, 0);
  attn_mfma<<<dim3(32, 8), 256, 0, stream>>>(proj2B, att2B, 2047);
  gemm_rm<<<dim3(256, 1), 256, 0, stream>>>(att2B, 128, ba_wout, ba_bout, boutB,
                                            16376, 128, 128, 0, 0);
  final_bp<<<dim3(4094), 256, 0, stream>>>(boutB, bpW, bpb, outF + 2097152, 16376);
}

// Round 4
// 853.769 us; speedup vs baseline: 2.4566x; 1.2373x over previous
//
#include <hip/hip_runtime.h>
#include <hip/hip_bf16.h>
#include <math.h>
#include <stdint.h>

// ---------------------------------------------------------------------------
// SceneSegmenter Round 4: ALL GEMMs moved to bf16 MFMA (16x16x32), fp32 accum.
// Attention unchanged from passing Round 3 except packed bf16 converts.
// Layouts: token-major activations (S, B, D) flat, row = s*8+b.
// ---------------------------------------------------------------------------

#define DEV static __device__ __forceinline__

typedef __attribute__((ext_vector_type(8))) short bf16x8;   // 8 bf16 (4 VGPRs)
typedef __attribute__((ext_vector_type(4))) float f32x4;    // MFMA C/D

DEV uint32_t pk2bf(float a, float b) {       // packed fp32x2 -> bf16x2 (RNE)
  __hip_bfloat162 h = __float22bfloat162_rn(make_float2(a, b));
  return *(uint32_t*)&h;
}
DEV uint2 cvt4(float4 f) {                   // 4 fp32 -> 4 bf16
  return make_uint2(pk2bf(f.x, f.y), pk2bf(f.z, f.w));
}

// ---------------------------------------------------------------------------
// bf16 MFMA GEMM: C[M x N](ldc) = act(A[M x K](lda) @ W[N x K]^T + bias)
// 256 thr = 4 waves (2x2 over a 128x128 tile); BK=64; K % 64 == 0.
// LDS: As/Ws 128 rows x pitch 72 shorts (144 B, 16B-aligned, 2-way banks=free).
// Fragment layouts (verified m89/m91): A/B row-major [row][k] 8-contig bf16;
// C/D col = lane&15, row = quad*4 + reg.
// remap=1: out row r = (m & 2047)*8 + (m >> 11)   ((B,S)->(S,B))
// ---------------------------------------------------------------------------
__global__ __launch_bounds__(256) void gemm_mfma(
    const float* __restrict__ A, int lda,
    const float* __restrict__ W,
    const float* __restrict__ bias,
    float* __restrict__ C, int ldc,
    int M, int K, int relu, int remap)
{
  __shared__ __align__(16) uint16_t As[128 * 72];
  __shared__ __align__(16) uint16_t Ws[128 * 72];

  const int t  = threadIdx.x;
  const int m0 = blockIdx.x * 128;
  const int n0 = blockIdx.y * 128;
  const int w  = t >> 6, l = t & 63;
  const int ln = l & 15, qd = l >> 4;
  const int wr = w & 1, wc = w >> 1;

  f32x4 acc[4][4];
#pragma unroll
  for (int i = 0; i < 4; ++i)
#pragma unroll
    for (int j = 0; j < 4; ++j) acc[i][j] = (f32x4){0.f, 0.f, 0.f, 0.f};

  const int rr = t >> 4;          // 0..15: row within 16-row group
  const int cl = (t & 15) * 4;    // float col within 64-chunk

  for (int k0 = 0; k0 < K; k0 += 64) {
    __syncthreads();
    // stage A tile (rows m0..m0+127, cols k0..k0+63), coalesced 16 lanes/row
#pragma unroll
    for (int i = 0; i < 8; ++i) {
      int m = m0 + rr + 16 * i;
      int mc = m < M ? m : M - 1;
      float4 f = *(const float4*)(A + (size_t)mc * lda + k0 + cl);
      *(uint2*)(As + (size_t)(rr + 16 * i) * 72 + cl) = cvt4(f);
    }
    // stage W tile (rows n0..n0+127) — N always a multiple of 128 here
#pragma unroll
    for (int i = 0; i < 8; ++i) {
      int n = n0 + rr + 16 * i;
      float4 f = *(const float4*)(W + (size_t)n * K + k0 + cl);
      *(uint2*)(Ws + (size_t)(rr + 16 * i) * 72 + cl) = cvt4(f);
    }
    __syncthreads();
#pragma unroll
    for (int ks = 0; ks < 2; ++ks) {
      bf16x8 af[4], bf[4];
#pragma unroll
      for (int mf = 0; mf < 4; ++mf)
        af[mf] = *(const bf16x8*)(As + (size_t)(wr * 64 + mf * 16 + ln) * 72 + ks * 32 + qd * 8);
#pragma unroll
      for (int nf = 0; nf < 4; ++nf)
        bf[nf] = *(const bf16x8*)(Ws + (size_t)(wc * 64 + nf * 16 + ln) * 72 + ks * 32 + qd * 8);
#pragma unroll
      for (int mf = 0; mf < 4; ++mf)
#pragma unroll
        for (int nf = 0; nf < 4; ++nf)
          acc[mf][nf] = __builtin_amdgcn_mfma_f32_16x16x32_bf16(af[mf], bf[nf], acc[mf][nf], 0, 0, 0);
    }
  }

  // epilogue: C rows = m0 + wr*64 + mf*16 + qd*4 + r, cols = n0 + wc*64 + nf*16 + ln
#pragma unroll
  for (int mf = 0; mf < 4; ++mf) {
#pragma unroll
    for (int r = 0; r < 4; ++r) {
      int m = m0 + wr * 64 + mf * 16 + qd * 4 + r;
      if (m < M) {
        size_t ro = remap ? (size_t)((m & 2047) * 8 + (m >> 11)) : (size_t)m;
#pragma unroll
        for (int nf = 0; nf < 4; ++nf) {
          int n = n0 + wc * 64 + nf * 16 + ln;
          float v = acc[mf][nf][r] + bias[n];
          if (relu) v = fmaxf(v, 0.f);
          C[ro * (size_t)ldc + n] = v;
        }
      }
    }
  }
}

// ---------------------------------------------------------------------------
// becat MFMA GEMM: b0[16376 x 128] = relu(cat(left,right) @ beW^T + beb).
// A rows synthesized on the fly from csum (S,B,128); K=256 fixed.
// ---------------------------------------------------------------------------
__global__ __launch_bounds__(256) void gemm_becat_mfma(
    const float* __restrict__ csum,
    const float* __restrict__ W, const float* __restrict__ bias,
    float* __restrict__ C)
{
  __shared__ __align__(16) uint16_t As[128 * 72];
  __shared__ __align__(16) uint16_t Ws[128 * 72];

  const int M = 16376, K = 256;
  const int t  = threadIdx.x;
  const int m0 = blockIdx.x * 128;
  const int w  = t >> 6, l = t & 63;
  const int ln = l & 15, qd = l >> 4;
  const int wr = w & 1, wc = w >> 1;

  f32x4 acc[4][4];
#pragma unroll
  for (int i = 0; i < 4; ++i)
#pragma unroll
    for (int j = 0; j < 4; ++j) acc[i][j] = (f32x4){0.f, 0.f, 0.f, 0.f};

  const int rr = t >> 4;
  const int cl = (t & 15) * 4;

  for (int k0 = 0; k0 < K; k0 += 64) {
    __syncthreads();
#pragma unroll
    for (int i = 0; i < 8; ++i) {
      int m = m0 + rr + 16 * i;
      int mc = m < M ? m : M - 1;
      int j = mc >> 3, bb = mc & 7;
      int kk = k0 + cl;
      float4 f;
      if (kk < 128) {
        float4 v = *(const float4*)(csum + (size_t)mc * 128 + kk);
        float s = 1.f / (float)(j + 1);
        f = make_float4(v.x * s, v.y * s, v.z * s, v.w * s);
      } else {
        int d = kk - 128;
        float4 c0 = *(const float4*)(csum + (size_t)mc * 128 + d);
        float4 ct = *(const float4*)(csum + (size_t)(16376 + bb) * 128 + d);
        float s = 1.f / (float)(2047 - j);
        f = make_float4((ct.x - c0.x) * s, (ct.y - c0.y) * s,
                        (ct.z - c0.z) * s, (ct.w - c0.w) * s);
      }
      *(uint2*)(As + (size_t)(rr + 16 * i) * 72 + cl) = cvt4(f);
    }
#pragma unroll
    for (int i = 0; i < 8; ++i) {
      int n = rr + 16 * i;   // N = 128
      float4 f = *(const float4*)(W + (size_t)n * K + k0 + cl);
      *(uint2*)(Ws + (size_t)(rr + 16 * i) * 72 + cl) = cvt4(f);
    }
    __syncthreads();
#pragma unroll
    for (int ks = 0; ks < 2; ++ks) {
      bf16x8 af[4], bf[4];
#pragma unroll
      for (int mf = 0; mf < 4; ++mf)
        af[mf] = *(const bf16x8*)(As + (size_t)(wr * 64 + mf * 16 + ln) * 72 + ks * 32 + qd * 8);
#pragma unroll
      for (int nf = 0; nf < 4; ++nf)
        bf[nf] = *(const bf16x8*)(Ws + (size_t)(wc * 64 + nf * 16 + ln) * 72 + ks * 32 + qd * 8);
#pragma unroll
      for (int mf = 0; mf < 4; ++mf)
#pragma unroll
        for (int nf = 0; nf < 4; ++nf)
          acc[mf][nf] = __builtin_amdgcn_mfma_f32_16x16x32_bf16(af[mf], bf[nf], acc[mf][nf], 0, 0, 0);
    }
  }

#pragma unroll
  for (int mf = 0; mf < 4; ++mf) {
#pragma unroll
    for (int r = 0; r < 4; ++r) {
      int m = m0 + wr * 64 + mf * 16 + qd * 4 + r;
      if (m < M) {
#pragma unroll
        for (int nf = 0; nf < 4; ++nf) {
          int n = wc * 64 + nf * 16 + ln;
          float v = fmaxf(acc[mf][nf][r] + bias[n], 0.f);
          C[(size_t)m * 128 + n] = v;
        }
      }
    }
  }
}

// ---------------------------------------------------------------------------
// Flash attention, bf16 MFMA (unchanged structure from passing Round 3;
// packed converts replace manual f2bf).
// ---------------------------------------------------------------------------
__global__ __launch_bounds__(256) void attn_mfma(
    const float* __restrict__ proj, float* __restrict__ out, int Slen)
{
  __shared__ __align__(16) uint16_t KsL[64 * 136];     // [key][k], pitch 136
  __shared__ __align__(16) uint16_t VtL[128 * 72];     // [d][k'],  pitch 72
  __shared__ __align__(16) uint16_t PbL[4][16 * 72];   // per-wave [q][k']

  const int t  = threadIdx.x;
  const int b  = blockIdx.y;
  const int q0 = blockIdx.x * 64;
  const int w  = t >> 6;
  const int l  = t & 63;
  const int ln = l & 15;
  const int qd = l >> 4;
  const float scl = 0.08838834764831845f;   // 1/sqrt(128)

  bf16x8 qf[4];
  {
    int qrow = q0 + w * 16 + ln;
    int qc = qrow < Slen ? qrow : Slen - 1;
    const float* qp = proj + ((size_t)qc * 8 + b) * 384 + qd * 8;
#pragma unroll
    for (int ks = 0; ks < 4; ++ks) {
      float4 f0 = *(const float4*)(qp + ks * 32);
      float4 f1 = *(const float4*)(qp + ks * 32 + 4);
      union { bf16x8 v; uint2 u[2]; } pk;
      pk.u[0] = cvt4(make_float4(f0.x * scl, f0.y * scl, f0.z * scl, f0.w * scl));
      pk.u[1] = cvt4(make_float4(f1.x * scl, f1.y * scl, f1.z * scl, f1.w * scl));
      qf[ks] = pk.v;
    }
  }

  f32x4 oacc[8];
#pragma unroll
  for (int i = 0; i < 8; ++i) oacc[i] = (f32x4){0.f, 0.f, 0.f, 0.f};
  float mrow[4] = {-INFINITY, -INFINITY, -INFINITY, -INFINITY};
  float lrow[4] = {0.f, 0.f, 0.f, 0.f};

  const int ntiles = (Slen + 63) >> 6;
  for (int kt = 0; kt < ntiles; ++kt) {
    __syncthreads();
    { // stage K tile
      int key = t >> 2;
      int kb  = (t & 3) * 32;
      int kg  = kt * 64 + key;
      int kc  = kg < Slen ? kg : Slen - 1;
      const float* kp = proj + ((size_t)kc * 8 + b) * 384 + 128 + kb;
      uint16_t* dst = KsL + key * 136 + kb;
#pragma unroll
      for (int i = 0; i < 4; ++i) {
        float4 f0 = *(const float4*)(kp + i * 8);
        float4 f1 = *(const float4*)(kp + i * 8 + 4);
        *(uint2*)(dst + i * 8)     = cvt4(f0);
        *(uint2*)(dst + i * 8 + 4) = cvt4(f1);
      }
    }
    { // stage V transposed+permuted: Vt[d][k'], keys (k, k+16) packed b32
      int pi  = t & 31;
      int k0o = (pi & 15) + ((pi >> 4) << 5);
      int d0  = (t >> 5) * 16;
      int kg0 = kt * 64 + k0o, kg1 = kg0 + 16;
      int kc0 = kg0 < Slen ? kg0 : Slen - 1;
      int kc1 = kg1 < Slen ? kg1 : Slen - 1;
      const float* v0p = proj + ((size_t)kc0 * 8 + b) * 384 + 256 + d0;
      const float* v1p = proj + ((size_t)kc1 * 8 + b) * 384 + 256 + d0;
      int kpos = (k0o & 15) * 4 + (k0o >> 4);
#pragma unroll
      for (int i = 0; i < 4; ++i) {
        float4 a = *(const float4*)(v0p + i * 4);
        float4 c = *(const float4*)(v1p + i * 4);
        float av[4] = {a.x, a.y, a.z, a.w};
        float cv[4] = {c.x, c.y, c.z, c.w};
#pragma unroll
        for (int j = 0; j < 4; ++j)
          *(uint32_t*)(VtL + (size_t)(d0 + i * 4 + j) * 72 + kpos) = pk2bf(av[j], cv[j]);
      }
    }
    __syncthreads();

    f32x4 sc[4];
#pragma unroll
    for (int nf = 0; nf < 4; ++nf) {
      f32x4 acc = (f32x4){0.f, 0.f, 0.f, 0.f};
#pragma unroll
      for (int ks = 0; ks < 4; ++ks) {
        bf16x8 kf = *(const bf16x8*)(KsL + (size_t)(nf * 16 + ln) * 136 + ks * 32 + qd * 8);
        acc = __builtin_amdgcn_mfma_f32_16x16x32_bf16(qf[ks], kf, acc, 0, 0, 0);
      }
      int key = kt * 64 + nf * 16 + ln;
      if (key >= Slen) { acc[0] = -1e30f; acc[1] = -1e30f; acc[2] = -1e30f; acc[3] = -1e30f; }
      sc[nf] = acc;
    }

    float alphaR[4];
#pragma unroll
    for (int r = 0; r < 4; ++r) {
      float mx = fmaxf(fmaxf(sc[0][r], sc[1][r]), fmaxf(sc[2][r], sc[3][r]));
      mx = fmaxf(mx, __shfl_xor(mx, 1));
      mx = fmaxf(mx, __shfl_xor(mx, 2));
      mx = fmaxf(mx, __shfl_xor(mx, 4));
      mx = fmaxf(mx, __shfl_xor(mx, 8));
      float mNew = fmaxf(mrow[r], mx);
      float p0 = __expf(sc[0][r] - mNew);
      float p1 = __expf(sc[1][r] - mNew);
      float p2 = __expf(sc[2][r] - mNew);
      float p3 = __expf(sc[3][r] - mNew);
      float ps = p0 + p1 + p2 + p3;
      ps += __shfl_xor(ps, 1);
      ps += __shfl_xor(ps, 2);
      ps += __shfl_xor(ps, 4);
      ps += __shfl_xor(ps, 8);
      float alpha = __expf(mrow[r] - mNew);
      mrow[r] = mNew;
      lrow[r] = lrow[r] * alpha + ps;
      alphaR[r] = alpha;
      uint2 pk;
      pk.x = pk2bf(p0, p1);
      pk.y = pk2bf(p2, p3);
      *(uint2*)(PbL[w] + (size_t)(qd * 4 + r) * 72 + ln * 4) = pk;
    }
#pragma unroll
    for (int no = 0; no < 8; ++no) {
#pragma unroll
      for (int r = 0; r < 4; ++r) oacc[no][r] *= alphaR[r];
    }
    __asm__ volatile("s_waitcnt lgkmcnt(0)" ::: "memory");

#pragma unroll
    for (int ks2 = 0; ks2 < 2; ++ks2) {
      bf16x8 af = *(const bf16x8*)(PbL[w] + (size_t)ln * 72 + ks2 * 32 + qd * 8);
#pragma unroll
      for (int no = 0; no < 8; ++no) {
        bf16x8 vf = *(const bf16x8*)(VtL + (size_t)(no * 16 + ln) * 72 + ks2 * 32 + qd * 8);
        oacc[no] = __builtin_amdgcn_mfma_f32_16x16x32_bf16(af, vf, oacc[no], 0, 0, 0);
      }
    }
  }

#pragma unroll
  for (int r = 0; r < 4; ++r) {
    int qg = q0 + w * 16 + qd * 4 + r;
    if (qg < Slen) {
      float inv = 1.f / lrow[r];
      float* dst = out + ((size_t)qg * 8 + b) * 128 + ln;
#pragma unroll
      for (int no = 0; no < 8; ++no) dst[no * 16] = oacc[no][r] * inv;
    }
  }
}

// ---------------------------------------------------------------------------
// Cumsum + final head (unchanged, passing).
// ---------------------------------------------------------------------------
__global__ void cumsum_p1(const float* __restrict__ e, float* __restrict__ csum,
                          float* __restrict__ part)
{
  int chunk = blockIdx.x, b = blockIdx.y, d = threadIdx.x;
  float run = 0.f;
  int s0 = chunk * 128;
  for (int s = 0; s < 128; ++s) {
    size_t idx = ((size_t)(s0 + s) * 8 + b) * 128 + d;
    run += e[idx];
    csum[idx] = run;
  }
  part[(b * 16 + chunk) * 128 + d] = run;
}

__global__ void cumsum_p2(float* __restrict__ part)
{
  int b = blockIdx.x, d = threadIdx.x;
  float run = 0.f;
  for (int c = 0; c < 16; ++c) {
    float v = part[(b * 16 + c) * 128 + d];
    part[(b * 16 + c) * 128 + d] = run;
    run += v;
  }
}

__global__ void cumsum_p3(float* __restrict__ csum, const float* __restrict__ part)
{
  int chunk = blockIdx.x, b = blockIdx.y, d = threadIdx.x;
  float off = part[(b * 16 + chunk) * 128 + d];
  int s0 = chunk * 128;
  for (int s = 0; s < 128; ++s)
    csum[((size_t)(s0 + s) * 8 + b) * 128 + d] += off;
}

__global__ __launch_bounds__(256) void final_bp(
    const float* __restrict__ bout, const float* __restrict__ bpW,
    const float* __restrict__ bpb, float* __restrict__ out, int M)
{
  int row  = blockIdx.x * 4 + (threadIdx.x >> 6);
  int lane = threadIdx.x & 63;
  if (row >= M) return;
  const float* src = bout + (size_t)row * 128;
  float2 v = *(const float2*)(src + lane * 2);
  float2 w = *(const float2*)(bpW + lane * 2);
  float p = v.x * w.x + v.y * w.y;
  p += __shfl_xor(p, 1);  p += __shfl_xor(p, 2);  p += __shfl_xor(p, 4);
  p += __shfl_xor(p, 8);  p += __shfl_xor(p, 16); p += __shfl_xor(p, 32);
  if (lane == 0) out[row] = 1.f / (1.f + __expf(-(p + bpb[0])));
}

// ---------------------------------------------------------------------------
extern "C" void kernel_launch(void* const* d_in, const int* in_sizes, int n_in,
                              void* d_out, int out_size, void* d_ws, size_t ws_size,
                              hipStream_t stream)
{
  const float* x       = (const float*)d_in[0];
  const float* pW      = (const float*)d_in[1];
  const float* pb      = (const float*)d_in[2];
  const float* cW      = (const float*)d_in[3];
  const float* cb      = (const float*)d_in[4];
  const float* aW      = (const float*)d_in[5];
  const float* ab      = (const float*)d_in[6];
  const float* uW      = (const float*)d_in[7];
  const float* ub      = (const float*)d_in[8];
  const float* eW      = (const float*)d_in[9];
  const float* eb      = (const float*)d_in[10];
  const float* la_win  = (const float*)d_in[11];
  const float* la_bin  = (const float*)d_in[12];
  const float* la_wout = (const float*)d_in[13];
  const float* la_bout = (const float*)d_in[14];
  const float* beW     = (const float*)d_in[15];
  const float* beb     = (const float*)d_in[16];
  const float* ba_win  = (const float*)d_in[17];
  const float* ba_bin  = (const float*)d_in[18];
  const float* ba_wout = (const float*)d_in[19];
  const float* ba_bout = (const float*)d_in[20];
  const float* bpW     = (const float*)d_in[21];
  const float* bpb     = (const float*)d_in[22];

  float* ws   = (float*)d_ws;
  float* outF = (float*)d_out;

  float* featsB = ws;                 // 16384*512
  float* e0B    = outF;               // 16384*128 (scratch until out-proj 1)
  float* proj1B = ws;                 // 16384*384
  float* att1B  = ws + 6291456;       // 16384*128
  float* csumB  = ws;                 // 16384*128
  float* partB  = ws + 2097152;       // 8*16*128
  float* b0B    = ws + 6291456;       // 16376*128
  float* proj2B = ws;                 // 16376*384
  float* att2B  = ws + 6291456;       // 16376*128
  float* boutB  = ws;                 // 16376*128

  // 1. feats = relu(segment linears), one MFMA GEMM per segment
  gemm_mfma<<<dim3(128, 1), 256, 0, stream>>>(x,        3584, pW, pb, featsB,       512, 16384, 2048, 1, 0);
  gemm_mfma<<<dim3(128, 1), 256, 0, stream>>>(x + 2048, 3584, cW, cb, featsB + 128, 512, 16384,  512, 1, 0);
  gemm_mfma<<<dim3(128, 1), 256, 0, stream>>>(x + 2560, 3584, aW, ab, featsB + 256, 512, 16384,  512, 1, 0);
  gemm_mfma<<<dim3(128, 1), 256, 0, stream>>>(x + 3072, 3584, uW, ub, featsB + 384, 512, 16384,  512, 1, 0);
  // 2. e0 = relu(feats @ eW^T + eb), remapped (B,S)->(S,B)
  gemm_mfma<<<dim3(128, 1), 256, 0, stream>>>(featsB, 512, eW, eb, e0B, 128, 16384, 512, 1, 1);
  // 3. proj1 = e0 @ la_win^T + la_bin
  gemm_mfma<<<dim3(128, 3), 256, 0, stream>>>(e0B, 128, la_win, la_bin, proj1B, 384, 16384, 128, 0, 0);
  // 4. att1
  attn_mfma<<<dim3(32, 8), 256, 0, stream>>>(proj1B, att1B, 2048);
  // 5. e = att1 @ la_wout^T + la_bout -> d_out
  gemm_mfma<<<dim3(128, 1), 256, 0, stream>>>(att1B, 128, la_wout, la_bout, outF, 128, 16384, 128, 0, 0);
  // 6-8. csum
  cumsum_p1<<<dim3(16, 8), 128, 0, stream>>>(outF, csumB, partB);
  cumsum_p2<<<dim3(8), 128, 0, stream>>>(partB);
  cumsum_p3<<<dim3(16, 8), 128, 0, stream>>>(csumB, partB);
  // 9. b0 = relu(cat(left,right) @ beW^T + beb)
  gemm_becat_mfma<<<dim3(128), 256, 0, stream>>>(csumB, beW, beb, b0B);
  // 10. proj2
  gemm_mfma<<<dim3(128, 3), 256, 0, stream>>>(b0B, 128, ba_win, ba_bin, proj2B, 384, 16376, 128, 0, 0);
  // 11. att2
  attn_mfma<<<dim3(32, 8), 256, 0, stream>>>(proj2B, att2B, 2047);
  // 12. bout
  gemm_mfma<<<dim3(128, 1), 256, 0, stream>>>(att2B, 128, ba_wout, ba_bout, boutB, 128, 16376, 128, 0, 0);
  // 13. b = sigmoid head -> d_out tail
  final_bp<<<dim3(4094), 256, 0, stream>>>(boutB, bpW, bpb, outF + 2097152, 16376);
}

// Round 5
// 676.781 us; speedup vs baseline: 3.0990x; 1.2615x over previous
//
#include <hip/hip_runtime.h>
#include <hip/hip_bf16.h>
#include <math.h>
#include <stdint.h>

// ---------------------------------------------------------------------------
// SceneSegmenter Round 5: occupancy round.
//  - attention: 2-way split-K flash (512 blocks = 2/CU) + exact combine
//  - GEMMs: BM=64 x BN=128 tile (full-machine grids), feats fused 4-seg
//  - cumsum widened to 256 blocks
// Layouts: token-major activations (S, B, D) flat, row = s*8+b.
// ---------------------------------------------------------------------------

#define DEV static __device__ __forceinline__

typedef __attribute__((ext_vector_type(8))) short bf16x8;   // 8 bf16 (4 VGPRs)
typedef __attribute__((ext_vector_type(4))) float f32x4;    // MFMA C/D

DEV uint32_t pk2bf(float a, float b) {       // packed fp32x2 -> bf16x2 (RNE)
  __hip_bfloat162 h = __float22bfloat162_rn(make_float2(a, b));
  return *(uint32_t*)&h;
}
DEV uint2 cvt4(float4 f) {                   // 4 fp32 -> 4 bf16
  return make_uint2(pk2bf(f.x, f.y), pk2bf(f.z, f.w));
}

// ---------------------------------------------------------------------------
// bf16 MFMA GEMM, BM=64 x BN=128, BK=64, 256 thr = 4 waves (each wave: 64
// rows x 32 cols). K % 64 == 0. Fragment layouts verified m89/m91.
// remap=1: out row r = (m & 2047)*8 + (m >> 11)   ((B,S)->(S,B))
// ---------------------------------------------------------------------------
__global__ __launch_bounds__(256) void gemm_mfma64(
    const float* __restrict__ A, int lda,
    const float* __restrict__ W,
    const float* __restrict__ bias,
    float* __restrict__ C, int ldc,
    int M, int K, int relu, int remap)
{
  __shared__ __align__(16) uint16_t As[64 * 72];
  __shared__ __align__(16) uint16_t Ws[128 * 72];

  const int t  = threadIdx.x;
  const int m0 = blockIdx.x * 64;
  const int n0 = blockIdx.y * 128;
  const int w  = t >> 6, l = t & 63;
  const int ln = l & 15, qd = l >> 4;

  f32x4 acc[4][2];
#pragma unroll
  for (int i = 0; i < 4; ++i) { acc[i][0] = (f32x4){0,0,0,0}; acc[i][1] = (f32x4){0,0,0,0}; }

  const int rr = t >> 4;          // 0..15
  const int cl = (t & 15) * 4;    // float col within 64-chunk

  for (int k0 = 0; k0 < K; k0 += 64) {
    __syncthreads();
#pragma unroll
    for (int i = 0; i < 4; ++i) {           // A tile: 64 rows
      int m = m0 + rr + 16 * i;
      int mc = m < M ? m : M - 1;
      float4 f = *(const float4*)(A + (size_t)mc * lda + k0 + cl);
      *(uint2*)(As + (size_t)(rr + 16 * i) * 72 + cl) = cvt4(f);
    }
#pragma unroll
    for (int i = 0; i < 8; ++i) {           // W tile: 128 rows
      int n = n0 + rr + 16 * i;
      float4 f = *(const float4*)(W + (size_t)n * K + k0 + cl);
      *(uint2*)(Ws + (size_t)(rr + 16 * i) * 72 + cl) = cvt4(f);
    }
    __syncthreads();
#pragma unroll
    for (int ks = 0; ks < 2; ++ks) {
      bf16x8 af[4], bf[2];
#pragma unroll
      for (int mf = 0; mf < 4; ++mf)
        af[mf] = *(const bf16x8*)(As + (size_t)(mf * 16 + ln) * 72 + ks * 32 + qd * 8);
#pragma unroll
      for (int nf = 0; nf < 2; ++nf)
        bf[nf] = *(const bf16x8*)(Ws + (size_t)(w * 32 + nf * 16 + ln) * 72 + ks * 32 + qd * 8);
#pragma unroll
      for (int mf = 0; mf < 4; ++mf)
#pragma unroll
        for (int nf = 0; nf < 2; ++nf)
          acc[mf][nf] = __builtin_amdgcn_mfma_f32_16x16x32_bf16(af[mf], bf[nf], acc[mf][nf], 0, 0, 0);
    }
  }

#pragma unroll
  for (int mf = 0; mf < 4; ++mf) {
#pragma unroll
    for (int r = 0; r < 4; ++r) {
      int m = m0 + mf * 16 + qd * 4 + r;
      if (m < M) {
        size_t ro = remap ? (size_t)((m & 2047) * 8 + (m >> 11)) : (size_t)m;
#pragma unroll
        for (int nf = 0; nf < 2; ++nf) {
          int n = n0 + w * 32 + nf * 16 + ln;
          float v = acc[mf][nf][r] + bias[n];
          if (relu) v = fmaxf(v, 0.f);
          C[ro * (size_t)ldc + n] = v;
        }
      }
    }
  }
}

// ---------------------------------------------------------------------------
// Fused 4-segment feats GEMM: blockIdx.y = segment, BM=64.
// feats[16384 x 512], segment n-cols at seg*128. 1024 blocks total.
// ---------------------------------------------------------------------------
__global__ __launch_bounds__(256) void gemm_feats64(
    const float* __restrict__ x,
    const float* __restrict__ pW, const float* __restrict__ pb,
    const float* __restrict__ cW, const float* __restrict__ cb,
    const float* __restrict__ aW, const float* __restrict__ ab,
    const float* __restrict__ uW, const float* __restrict__ ub,
    float* __restrict__ feats)
{
  __shared__ __align__(16) uint16_t As[64 * 72];
  __shared__ __align__(16) uint16_t Ws[128 * 72];

  const int seg = blockIdx.y;
  const float* W; const float* bias; int kbase, Kseg;
  if (seg == 0)      { W = pW; bias = pb; kbase = 0;    Kseg = 2048; }
  else if (seg == 1) { W = cW; bias = cb; kbase = 2048; Kseg = 512; }
  else if (seg == 2) { W = aW; bias = ab; kbase = 2560; Kseg = 512; }
  else               { W = uW; bias = ub; kbase = 3072; Kseg = 512; }

  const int t  = threadIdx.x;
  const int m0 = blockIdx.x * 64;
  const int w  = t >> 6, l = t & 63;
  const int ln = l & 15, qd = l >> 4;

  f32x4 acc[4][2];
#pragma unroll
  for (int i = 0; i < 4; ++i) { acc[i][0] = (f32x4){0,0,0,0}; acc[i][1] = (f32x4){0,0,0,0}; }

  const int rr = t >> 4;
  const int cl = (t & 15) * 4;

  for (int k0 = 0; k0 < Kseg; k0 += 64) {
    __syncthreads();
#pragma unroll
    for (int i = 0; i < 4; ++i) {
      int m = m0 + rr + 16 * i;
      float4 f = *(const float4*)(x + (size_t)m * 3584 + kbase + k0 + cl);
      *(uint2*)(As + (size_t)(rr + 16 * i) * 72 + cl) = cvt4(f);
    }
#pragma unroll
    for (int i = 0; i < 8; ++i) {
      int n = rr + 16 * i;
      float4 f = *(const float4*)(W + (size_t)n * Kseg + k0 + cl);
      *(uint2*)(Ws + (size_t)(rr + 16 * i) * 72 + cl) = cvt4(f);
    }
    __syncthreads();
#pragma unroll
    for (int ks = 0; ks < 2; ++ks) {
      bf16x8 af[4], bf[2];
#pragma unroll
      for (int mf = 0; mf < 4; ++mf)
        af[mf] = *(const bf16x8*)(As + (size_t)(mf * 16 + ln) * 72 + ks * 32 + qd * 8);
#pragma unroll
      for (int nf = 0; nf < 2; ++nf)
        bf[nf] = *(const bf16x8*)(Ws + (size_t)(w * 32 + nf * 16 + ln) * 72 + ks * 32 + qd * 8);
#pragma unroll
      for (int mf = 0; mf < 4; ++mf)
#pragma unroll
        for (int nf = 0; nf < 2; ++nf)
          acc[mf][nf] = __builtin_amdgcn_mfma_f32_16x16x32_bf16(af[mf], bf[nf], acc[mf][nf], 0, 0, 0);
    }
  }

#pragma unroll
  for (int mf = 0; mf < 4; ++mf) {
#pragma unroll
    for (int r = 0; r < 4; ++r) {
      int m = m0 + mf * 16 + qd * 4 + r;
#pragma unroll
      for (int nf = 0; nf < 2; ++nf) {
        int n = w * 32 + nf * 16 + ln;
        float v = fmaxf(acc[mf][nf][r] + bias[n], 0.f);
        feats[(size_t)m * 512 + seg * 128 + n] = v;
      }
    }
  }
}

// ---------------------------------------------------------------------------
// becat MFMA GEMM, BM=64: b0[16376 x 128] = relu(cat(left,right) @ beW^T + b).
// A rows synthesized from csum (S,B,128); K=256. 256 blocks.
// ---------------------------------------------------------------------------
__global__ __launch_bounds__(256) void gemm_becat64(
    const float* __restrict__ csum,
    const float* __restrict__ W, const float* __restrict__ bias,
    float* __restrict__ C)
{
  __shared__ __align__(16) uint16_t As[64 * 72];
  __shared__ __align__(16) uint16_t Ws[128 * 72];

  const int M = 16376, K = 256;
  const int t  = threadIdx.x;
  const int m0 = blockIdx.x * 64;
  const int w  = t >> 6, l = t & 63;
  const int ln = l & 15, qd = l >> 4;

  f32x4 acc[4][2];
#pragma unroll
  for (int i = 0; i < 4; ++i) { acc[i][0] = (f32x4){0,0,0,0}; acc[i][1] = (f32x4){0,0,0,0}; }

  const int rr = t >> 4;
  const int cl = (t & 15) * 4;

  for (int k0 = 0; k0 < K; k0 += 64) {
    __syncthreads();
#pragma unroll
    for (int i = 0; i < 4; ++i) {
      int m = m0 + rr + 16 * i;
      int mc = m < M ? m : M - 1;
      int j = mc >> 3, bb = mc & 7;
      int kk = k0 + cl;
      float4 f;
      if (kk < 128) {
        float4 v = *(const float4*)(csum + (size_t)mc * 128 + kk);
        float s = 1.f / (float)(j + 1);
        f = make_float4(v.x * s, v.y * s, v.z * s, v.w * s);
      } else {
        int d = kk - 128;
        float4 c0 = *(const float4*)(csum + (size_t)mc * 128 + d);
        float4 ct = *(const float4*)(csum + (size_t)(16376 + bb) * 128 + d);
        float s = 1.f / (float)(2047 - j);
        f = make_float4((ct.x - c0.x) * s, (ct.y - c0.y) * s,
                        (ct.z - c0.z) * s, (ct.w - c0.w) * s);
      }
      *(uint2*)(As + (size_t)(rr + 16 * i) * 72 + cl) = cvt4(f);
    }
#pragma unroll
    for (int i = 0; i < 8; ++i) {
      int n = rr + 16 * i;
      float4 f = *(const float4*)(W + (size_t)n * K + k0 + cl);
      *(uint2*)(Ws + (size_t)(rr + 16 * i) * 72 + cl) = cvt4(f);
    }
    __syncthreads();
#pragma unroll
    for (int ks = 0; ks < 2; ++ks) {
      bf16x8 af[4], bf[2];
#pragma unroll
      for (int mf = 0; mf < 4; ++mf)
        af[mf] = *(const bf16x8*)(As + (size_t)(mf * 16 + ln) * 72 + ks * 32 + qd * 8);
#pragma unroll
      for (int nf = 0; nf < 2; ++nf)
        bf[nf] = *(const bf16x8*)(Ws + (size_t)(w * 32 + nf * 16 + ln) * 72 + ks * 32 + qd * 8);
#pragma unroll
      for (int mf = 0; mf < 4; ++mf)
#pragma unroll
        for (int nf = 0; nf < 2; ++nf)
          acc[mf][nf] = __builtin_amdgcn_mfma_f32_16x16x32_bf16(af[mf], bf[nf], acc[mf][nf], 0, 0, 0);
    }
  }

#pragma unroll
  for (int mf = 0; mf < 4; ++mf) {
#pragma unroll
    for (int r = 0; r < 4; ++r) {
      int m = m0 + mf * 16 + qd * 4 + r;
      if (m < M) {
#pragma unroll
        for (int nf = 0; nf < 2; ++nf) {
          int n = w * 32 + nf * 16 + ln;
          C[(size_t)m * 128 + n] = fmaxf(acc[mf][nf][r] + bias[n], 0.f);
        }
      }
    }
  }
}

// ---------------------------------------------------------------------------
// Split-K flash attention, bf16 MFMA. blockIdx.z = split (keys [z*1024, end)).
// Stores UNNORMALIZED O partials + (m, l) per row; attn_combine merges.
// Structure otherwise identical to the passing Round-3/4 kernel.
// ---------------------------------------------------------------------------
__global__ __launch_bounds__(256) void attn_mfma_split(
    const float* __restrict__ proj, float* __restrict__ Opart,
    float* __restrict__ ml, int Slen)
{
  __shared__ __align__(16) uint16_t KsL[64 * 136];     // [key][k], pitch 136
  __shared__ __align__(16) uint16_t VtL[128 * 72];     // [d][k'],  pitch 72
  __shared__ __align__(16) uint16_t PbL[4][16 * 72];   // per-wave [q][k']

  const int t  = threadIdx.x;
  const int b  = blockIdx.y;
  const int q0 = blockIdx.x * 64;
  const int split = blockIdx.z;
  const int kbeg = split * 1024;
  const int kend = min(Slen, kbeg + 1024);
  const int w  = t >> 6;
  const int l  = t & 63;
  const int ln = l & 15;
  const int qd = l >> 4;
  const float scl = 0.08838834764831845f;   // 1/sqrt(128)

  bf16x8 qf[4];
  {
    int qrow = q0 + w * 16 + ln;
    int qc = qrow < Slen ? qrow : Slen - 1;
    const float* qp = proj + ((size_t)qc * 8 + b) * 384 + qd * 8;
#pragma unroll
    for (int ks = 0; ks < 4; ++ks) {
      float4 f0 = *(const float4*)(qp + ks * 32);
      float4 f1 = *(const float4*)(qp + ks * 32 + 4);
      union { bf16x8 v; uint2 u[2]; } pk;
      pk.u[0] = cvt4(make_float4(f0.x * scl, f0.y * scl, f0.z * scl, f0.w * scl));
      pk.u[1] = cvt4(make_float4(f1.x * scl, f1.y * scl, f1.z * scl, f1.w * scl));
      qf[ks] = pk.v;
    }
  }

  f32x4 oacc[8];
#pragma unroll
  for (int i = 0; i < 8; ++i) oacc[i] = (f32x4){0.f, 0.f, 0.f, 0.f};
  float mrow[4] = {-INFINITY, -INFINITY, -INFINITY, -INFINITY};
  float lrow[4] = {0.f, 0.f, 0.f, 0.f};

  const int ntiles = (kend - kbeg + 63) >> 6;
  for (int kt = 0; kt < ntiles; ++kt) {
    __syncthreads();
    { // stage K tile
      int key = t >> 2;
      int kb  = (t & 3) * 32;
      int kg  = kbeg + kt * 64 + key;
      int kc  = kg < Slen ? kg : Slen - 1;
      const float* kp = proj + ((size_t)kc * 8 + b) * 384 + 128 + kb;
      uint16_t* dst = KsL + key * 136 + kb;
#pragma unroll
      for (int i = 0; i < 4; ++i) {
        float4 f0 = *(const float4*)(kp + i * 8);
        float4 f1 = *(const float4*)(kp + i * 8 + 4);
        *(uint2*)(dst + i * 8)     = cvt4(f0);
        *(uint2*)(dst + i * 8 + 4) = cvt4(f1);
      }
    }
    { // stage V transposed+permuted: Vt[d][k'], keys (k, k+16) packed b32
      int pi  = t & 31;
      int k0o = (pi & 15) + ((pi >> 4) << 5);
      int d0  = (t >> 5) * 16;
      int kg0 = kbeg + kt * 64 + k0o, kg1 = kg0 + 16;
      int kc0 = kg0 < Slen ? kg0 : Slen - 1;
      int kc1 = kg1 < Slen ? kg1 : Slen - 1;
      const float* v0p = proj + ((size_t)kc0 * 8 + b) * 384 + 256 + d0;
      const float* v1p = proj + ((size_t)kc1 * 8 + b) * 384 + 256 + d0;
      int kpos = (k0o & 15) * 4 + (k0o >> 4);
#pragma unroll
      for (int i = 0; i < 4; ++i) {
        float4 a = *(const float4*)(v0p + i * 4);
        float4 c = *(const float4*)(v1p + i * 4);
        float av[4] = {a.x, a.y, a.z, a.w};
        float cv[4] = {c.x, c.y, c.z, c.w};
#pragma unroll
        for (int j = 0; j < 4; ++j)
          *(uint32_t*)(VtL + (size_t)(d0 + i * 4 + j) * 72 + kpos) = pk2bf(av[j], cv[j]);
      }
    }
    __syncthreads();

    f32x4 sc[4];
#pragma unroll
    for (int nf = 0; nf < 4; ++nf) {
      f32x4 acc = (f32x4){0.f, 0.f, 0.f, 0.f};
#pragma unroll
      for (int ks = 0; ks < 4; ++ks) {
        bf16x8 kf = *(const bf16x8*)(KsL + (size_t)(nf * 16 + ln) * 136 + ks * 32 + qd * 8);
        acc = __builtin_amdgcn_mfma_f32_16x16x32_bf16(qf[ks], kf, acc, 0, 0, 0);
      }
      int key = kbeg + kt * 64 + nf * 16 + ln;
      if (key >= kend) { acc[0] = -1e30f; acc[1] = -1e30f; acc[2] = -1e30f; acc[3] = -1e30f; }
      sc[nf] = acc;
    }

    float alphaR[4];
#pragma unroll
    for (int r = 0; r < 4; ++r) {
      float mx = fmaxf(fmaxf(sc[0][r], sc[1][r]), fmaxf(sc[2][r], sc[3][r]));
      mx = fmaxf(mx, __shfl_xor(mx, 1));
      mx = fmaxf(mx, __shfl_xor(mx, 2));
      mx = fmaxf(mx, __shfl_xor(mx, 4));
      mx = fmaxf(mx, __shfl_xor(mx, 8));
      float mNew = fmaxf(mrow[r], mx);
      float p0 = __expf(sc[0][r] - mNew);
      float p1 = __expf(sc[1][r] - mNew);
      float p2 = __expf(sc[2][r] - mNew);
      float p3 = __expf(sc[3][r] - mNew);
      float ps = p0 + p1 + p2 + p3;
      ps += __shfl_xor(ps, 1);
      ps += __shfl_xor(ps, 2);
      ps += __shfl_xor(ps, 4);
      ps += __shfl_xor(ps, 8);
      float alpha = __expf(mrow[r] - mNew);
      mrow[r] = mNew;
      lrow[r] = lrow[r] * alpha + ps;
      alphaR[r] = alpha;
      uint2 pk;
      pk.x = pk2bf(p0, p1);
      pk.y = pk2bf(p2, p3);
      *(uint2*)(PbL[w] + (size_t)(qd * 4 + r) * 72 + ln * 4) = pk;
    }
#pragma unroll
    for (int no = 0; no < 8; ++no) {
#pragma unroll
      for (int r = 0; r < 4; ++r) oacc[no][r] *= alphaR[r];
    }
    __asm__ volatile("s_waitcnt lgkmcnt(0)" ::: "memory");

#pragma unroll
    for (int ks2 = 0; ks2 < 2; ++ks2) {
      bf16x8 af = *(const bf16x8*)(PbL[w] + (size_t)ln * 72 + ks2 * 32 + qd * 8);
#pragma unroll
      for (int no = 0; no < 8; ++no) {
        bf16x8 vf = *(const bf16x8*)(VtL + (size_t)(no * 16 + ln) * 72 + ks2 * 32 + qd * 8);
        oacc[no] = __builtin_amdgcn_mfma_f32_16x16x32_bf16(af, vf, oacc[no], 0, 0, 0);
      }
    }
  }

  // store unnormalized partials + (m, l)
#pragma unroll
  for (int r = 0; r < 4; ++r) {
    int qg = q0 + w * 16 + qd * 4 + r;
    if (qg < Slen) {
      size_t row = (size_t)qg * 8 + b;
      float* dst = Opart + ((size_t)split * 16384 + row) * 128 + ln;
#pragma unroll
      for (int no = 0; no < 8; ++no) dst[no * 16] = oacc[no][r];
      if (ln == 0) {
        ml[((size_t)split * 16384 + row) * 2 + 0] = mrow[r];
        ml[((size_t)split * 16384 + row) * 2 + 1] = lrow[r];
      }
    }
  }
}

// Exact merge of 2 split partials: out = (O0*w0 + O1*w1) / (l0*w0 + l1*w1).
__global__ __launch_bounds__(256) void attn_combine(
    const float* __restrict__ Opart, const float* __restrict__ ml,
    float* __restrict__ out, int rows)
{
  int idx = blockIdx.x * 256 + threadIdx.x;   // one per (row, 4-float group)
  int row = idx >> 5;
  int d   = (idx & 31) * 4;
  if (row >= rows) return;
  float m0 = ml[(size_t)row * 2 + 0],          l0 = ml[(size_t)row * 2 + 1];
  float m1 = ml[((size_t)16384 + row) * 2 + 0], l1 = ml[((size_t)16384 + row) * 2 + 1];
  float M = fmaxf(m0, m1);
  float w0 = __expf(m0 - M), w1 = __expf(m1 - M);
  float inv = 1.f / (l0 * w0 + l1 * w1);
  float4 a = *(const float4*)(Opart + (size_t)row * 128 + d);
  float4 c = *(const float4*)(Opart + ((size_t)16384 + row) * 128 + d);
  float4 o = make_float4((a.x * w0 + c.x * w1) * inv, (a.y * w0 + c.y * w1) * inv,
                         (a.z * w0 + c.z * w1) * inv, (a.w * w0 + c.w * w1) * inv);
  *(float4*)(out + (size_t)row * 128 + d) = o;
}

// ---------------------------------------------------------------------------
// Cumsum over s of e (S,B,128), 32 chunks x 64 rows (256 blocks).
// ---------------------------------------------------------------------------
__global__ void cumsum_p1(const float* __restrict__ e, float* __restrict__ csum,
                          float* __restrict__ part)
{
  int chunk = blockIdx.x, b = blockIdx.y, d = threadIdx.x;
  float run = 0.f;
  int s0 = chunk * 64;
  for (int s = 0; s < 64; ++s) {
    size_t idx = ((size_t)(s0 + s) * 8 + b) * 128 + d;
    run += e[idx];
    csum[idx] = run;
  }
  part[(b * 32 + chunk) * 128 + d] = run;
}

__global__ void cumsum_p2(float* __restrict__ part)
{
  int b = blockIdx.x, d = threadIdx.x;
  float run = 0.f;
  for (int c = 0; c < 32; ++c) {
    float v = part[(b * 32 + c) * 128 + d];
    part[(b * 32 + c) * 128 + d] = run;
    run += v;
  }
}

__global__ void cumsum_p3(float* __restrict__ csum, const float* __restrict__ part)
{
  int chunk = blockIdx.x, b = blockIdx.y, d = threadIdx.x;
  float off = part[(b * 32 + chunk) * 128 + d];
  int s0 = chunk * 64;
  for (int s = 0; s < 64; ++s)
    csum[((size_t)(s0 + s) * 8 + b) * 128 + d] += off;
}

// ---------------------------------------------------------------------------
// Final head (unchanged, passing).
// ---------------------------------------------------------------------------
__global__ __launch_bounds__(256) void final_bp(
    const float* __restrict__ bout, const float* __restrict__ bpW,
    const float* __restrict__ bpb, float* __restrict__ out, int M)
{
  int row  = blockIdx.x * 4 + (threadIdx.x >> 6);
  int lane = threadIdx.x & 63;
  if (row >= M) return;
  const float* src = bout + (size_t)row * 128;
  float2 v = *(const float2*)(src + lane * 2);
  float2 w = *(const float2*)(bpW + lane * 2);
  float p = v.x * w.x + v.y * w.y;
  p += __shfl_xor(p, 1);  p += __shfl_xor(p, 2);  p += __shfl_xor(p, 4);
  p += __shfl_xor(p, 8);  p += __shfl_xor(p, 16); p += __shfl_xor(p, 32);
  if (lane == 0) out[row] = 1.f / (1.f + __expf(-(p + bpb[0])));
}

// ---------------------------------------------------------------------------
extern "C" void kernel_launch(void* const* d_in, const int* in_sizes, int n_in,
                              void* d_out, int out_size, void* d_ws, size_t ws_size,
                              hipStream_t stream)
{
  const float* x       = (const float*)d_in[0];
  const float* pW      = (const float*)d_in[1];
  const float* pb      = (const float*)d_in[2];
  const float* cW      = (const float*)d_in[3];
  const float* cb      = (const float*)d_in[4];
  const float* aW      = (const float*)d_in[5];
  const float* ab      = (const float*)d_in[6];
  const float* uW      = (const float*)d_in[7];
  const float* ub      = (const float*)d_in[8];
  const float* eW      = (const float*)d_in[9];
  const float* eb      = (const float*)d_in[10];
  const float* la_win  = (const float*)d_in[11];
  const float* la_bin  = (const float*)d_in[12];
  const float* la_wout = (const float*)d_in[13];
  const float* la_bout = (const float*)d_in[14];
  const float* beW     = (const float*)d_in[15];
  const float* beb     = (const float*)d_in[16];
  const float* ba_win  = (const float*)d_in[17];
  const float* ba_bin  = (const float*)d_in[18];
  const float* ba_wout = (const float*)d_in[19];
  const float* ba_bout = (const float*)d_in[20];
  const float* bpW     = (const float*)d_in[21];
  const float* bpb     = (const float*)d_in[22];

  float* ws   = (float*)d_ws;
  float* outF = (float*)d_out;

  // Workspace plan (floats), serial aliasing:
  //  [0 .. 8,388,608)     featsB / proj1B(6.29M) / csumB(2.1M) / proj2B / boutB
  //  [2,097,152 ..)       partB (32K, coexists only with csum)
  //  [6,291,456 .. 8.39M) att1B / b0B / att2B (2.1M each, serial)
  //  [8,388,608 .. 12.6M) attention partials (2 splits x 2.1M)
  //  [12,582,912 ..)      ml (64K)
  float* featsB = ws;
  float* e0B    = outF;                // scratch until out-proj 1
  float* proj1B = ws;
  float* att1B  = ws + 6291456;
  float* csumB  = ws;
  float* partB  = ws + 2097152;
  float* b0B    = ws + 6291456;
  float* proj2B = ws;
  float* att2B  = ws + 6291456;
  float* boutB  = ws;
  float* OpartB = ws + 8388608;        // [split][16384][128]
  float* mlB    = ws + 12582912;       // [split][16384][2]

  // 1. feats = relu(segment linears), fused 4-segment, 1024 blocks
  gemm_feats64<<<dim3(256, 4), 256, 0, stream>>>(x, pW, pb, cW, cb, aW, ab, uW, ub, featsB);
  // 2. e0 = relu(feats @ eW^T + eb), remapped (B,S)->(S,B)
  gemm_mfma64<<<dim3(256, 1), 256, 0, stream>>>(featsB, 512, eW, eb, e0B, 128, 16384, 512, 1, 1);
  // 3. proj1 = e0 @ la_win^T + la_bin (768 blocks)
  gemm_mfma64<<<dim3(256, 3), 256, 0, stream>>>(e0B, 128, la_win, la_bin, proj1B, 384, 16384, 128, 0, 0);
  // 4. att1: split-K flash (512 blocks) + combine
  attn_mfma_split<<<dim3(32, 8, 2), 256, 0, stream>>>(proj1B, OpartB, mlB, 2048);
  attn_combine<<<dim3(2048), 256, 0, stream>>>(OpartB, mlB, att1B, 16384);
  // 5. e = att1 @ la_wout^T + la_bout -> d_out
  gemm_mfma64<<<dim3(256, 1), 256, 0, stream>>>(att1B, 128, la_wout, la_bout, outF, 128, 16384, 128, 0, 0);
  // 6-8. csum
  cumsum_p1<<<dim3(32, 8), 128, 0, stream>>>(outF, csumB, partB);
  cumsum_p2<<<dim3(8), 128, 0, stream>>>(partB);
  cumsum_p3<<<dim3(32, 8), 128, 0, stream>>>(csumB, partB);
  // 9. b0 = relu(cat(left,right) @ beW^T + beb)
  gemm_becat64<<<dim3(256), 256, 0, stream>>>(csumB, beW, beb, b0B);
  // 10. proj2
  gemm_mfma64<<<dim3(256, 3), 256, 0, stream>>>(b0B, 128, ba_win, ba_bin, proj2B, 384, 16376, 128, 0, 0);
  // 11. att2 (Slen = 2047) + combine (16376 rows -> 2047 blocks exactly)
  attn_mfma_split<<<dim3(32, 8, 2), 256, 0, stream>>>(proj2B, OpartB, mlB, 2047);
  attn_combine<<<dim3(2047), 256, 0, stream>>>(OpartB, mlB, att2B, 16376);
  // 12. bout
  gemm_mfma64<<<dim3(256, 1), 256, 0, stream>>>(att2B, 128, ba_wout, ba_bout, boutB, 128, 16376, 128, 0, 0);
  // 13. b = sigmoid head -> d_out tail
  final_bp<<<dim3(4094), 256, 0, stream>>>(boutB, bpW, bpb, outF + 2097152, 16376);
}